// Round 11
// baseline (330.004 us; speedup 1.0000x reference)
//
#include <hip/hip_runtime.h>

#define N_NODES 20000
#define N_EDGES 640000
#define HID 128
#define N_GRAPHS 32

#define SCAN_BLK 256
#define SCAN_NBLK ((N_NODES + SCAN_BLK - 1) / SCAN_BLK)  // 79

// ---------------------------------------------------------------------------
// K1: in-degree histogram over target nodes (col)
// ---------------------------------------------------------------------------
__global__ __launch_bounds__(256) void hist_k(const int* __restrict__ col,
                                              int* __restrict__ cnt) {
    int e = blockIdx.x * blockDim.x + threadIdx.x;
    if (e < N_EDGES) {
        int c = col[e];
        if ((unsigned)c < N_NODES) atomicAdd(&cnt[c], 1);
    }
}

// ---------------------------------------------------------------------------
// K2a: per-block sums of cnt (coalesced), 79 blocks x 256 thr
// ---------------------------------------------------------------------------
__global__ __launch_bounds__(SCAN_BLK) void scanA_k(const int* __restrict__ cnt,
                                                    int* __restrict__ blkSum) {
    __shared__ int wsum[SCAN_BLK / 64];
    const int b = blockIdx.x, t = threadIdx.x;
    const int i = b * SCAN_BLK + t;
    int v = (i < N_NODES) ? cnt[i] : 0;
#pragma unroll
    for (int o = 1; o < 64; o <<= 1) v += __shfl_xor(v, o);
    if ((t & 63) == 0) wsum[t >> 6] = v;
    __syncthreads();
    if (t == 0) {
        int s = 0;
#pragma unroll
        for (int w = 0; w < SCAN_BLK / 64; ++w) s += wsum[w];
        blkSum[b] = s;
    }
}

// ---------------------------------------------------------------------------
// K2b: per-block exclusive scan + block base from blkSum. Coalesced writes of
// offs/cursor/dinv. Thread owning node N-1 writes offs[N_NODES].
// ---------------------------------------------------------------------------
__global__ __launch_bounds__(SCAN_BLK) void scanB_k(const int* __restrict__ cnt,
                                                    const int* __restrict__ blkSum,
                                                    int* __restrict__ offs,
                                                    int* __restrict__ cursor,
                                                    float* __restrict__ dinv) {
    __shared__ int sm[SCAN_BLK];
    __shared__ int base_s;
    const int b = blockIdx.x, t = threadIdx.x;
    const int i = b * SCAN_BLK + t;
    const int v = (i < N_NODES) ? cnt[i] : 0;
    sm[t] = v;
    if (t == 0) {
        int s = 0;
        for (int k = 0; k < b; ++k) s += blkSum[k];
        base_s = s;
    }
    __syncthreads();
    // Hillis-Steele inclusive scan over 256 entries (8 rounds)
    for (int o = 1; o < SCAN_BLK; o <<= 1) {
        int add = (t >= o) ? sm[t - o] : 0;
        __syncthreads();
        sm[t] += add;
        __syncthreads();
    }
    if (i < N_NODES) {
        int excl = base_s + ((t > 0) ? sm[t - 1] : 0);
        offs[i] = excl;
        cursor[i] = excl;
        dinv[i] = rsqrtf((float)(v + 1));  // self-loop included, deg>=1 always
        if (i == N_NODES - 1) offs[N_NODES] = excl + v;
    }
}

// ---------------------------------------------------------------------------
// K3: CSR fill, src index ONLY (norm reconstructed in agg via dinv[src]).
// ---------------------------------------------------------------------------
__global__ __launch_bounds__(256) void fill_k(const int* __restrict__ row,
                                              const int* __restrict__ col,
                                              int* __restrict__ cursor,
                                              int* __restrict__ csr_src) {
    int e = blockIdx.x * blockDim.x + threadIdx.x;
    if (e < N_EDGES) {
        int c = col[e];
        int r = row[e];
        if ((unsigned)c < N_NODES && (unsigned)r < N_NODES) {
            int p = atomicAdd(&cursor[c], 1);
            csr_src[p] = r;
        }
    }
}

// ---------------------------------------------------------------------------
// K4: Y[20000,128] = X @ W (f32). Scalar-x structure: wave owns 8 rows
// (uniform addr -> s_load on SMEM pipe), lane owns 2 cols, LDS holds only a
// 64-row W chunk (32 KB). Per k: 1 ds_read_b64 per 16 fmaf -> VALU-bound.
// N_NODES = 625*32 exactly -> no bounds checks.
// ---------------------------------------------------------------------------
__global__ __launch_bounds__(256) void gemm128_k(const float* __restrict__ X,
                                                 const float* __restrict__ W,
                                                 float* __restrict__ Y) {
    __shared__ float wbuf[64 * 128];  // 32 KB
    const int t = threadIdx.x;
    const int lane = t & 63;
    const int wid = __builtin_amdgcn_readfirstlane(t >> 6);
    const int c2 = lane * 2;
    const int row0 = blockIdx.x * 32 + wid * 8;
    const float* Xr = X + (size_t)row0 * 128;
    float2 acc[8];
#pragma unroll
    for (int r = 0; r < 8; ++r) acc[r] = make_float2(0.f, 0.f);
#pragma unroll
    for (int kc = 0; kc < 2; ++kc) {
        __syncthreads();
#pragma unroll
        for (int i = 0; i < 8; ++i)
            ((float4*)wbuf)[t + i * 256] = ((const float4*)W)[kc * 2048 + t + i * 256];
        __syncthreads();
        const int kb = kc * 64;
        for (int k0 = 0; k0 < 64; k0 += 4) {
            float4 xa[8];
#pragma unroll
            for (int r = 0; r < 8; ++r)
                xa[r] = *(const float4*)&Xr[r * 128 + kb + k0];
#pragma unroll
            for (int kk = 0; kk < 4; ++kk) {
                float2 w = *(const float2*)&wbuf[(k0 + kk) * 128 + c2];
#pragma unroll
                for (int r = 0; r < 8; ++r) {
                    float xv = (&xa[r].x)[kk];  // kk compile-time (unrolled)
                    acc[r].x = fmaf(xv, w.x, acc[r].x);
                    acc[r].y = fmaf(xv, w.y, acc[r].y);
                }
            }
        }
    }
#pragma unroll
    for (int r = 0; r < 8; ++r)
        *(float2*)&Y[(size_t)(row0 + r) * 128 + c2] = acc[r];
}

// ---------------------------------------------------------------------------
// K5: GCN aggregation. TWO nodes per wave, float4/lane.
// Edge weight = dinv[src] (broadcast). OOB edge -> index 0, weight 0.
// out[c] = relu(dinv[c]*(sum_j dinv[src_j]*h[src_j] + dinv[c]*h[c]) + bias)
// ---------------------------------------------------------------------------
__global__ __launch_bounds__(256) void gcn_agg_k(const float* __restrict__ h,
                                                 const int* __restrict__ offs,
                                                 const int* __restrict__ src,
                                                 const float* __restrict__ dinv,
                                                 const float* __restrict__ bias,
                                                 float* __restrict__ out) {
    const int wave = threadIdx.x >> 6;
    const int lane = threadIdx.x & 63;
    const int half = lane >> 5;
    const int node = (blockIdx.x * 4 + wave) * 2 + half;
    const int c4 = (lane & 31) * 4;
    const int nd = (node < N_NODES) ? node : (N_NODES - 1);
    const float dc = dinv[nd];
    float4 hv = *(const float4*)&h[(size_t)nd * 128 + c4];
    float4 acc = make_float4(dc * hv.x, dc * hv.y, dc * hv.z, dc * hv.w);
    const int beg = offs[nd];
    const int deg = offs[nd + 1] - beg;
    const int mdeg = max(deg, __shfl(deg, lane ^ 32));
    for (int j = 0; j < mdeg; j += 4) {
        int i0 = (j + 0 < deg) ? beg + j + 0 : 0;
        int i1 = (j + 1 < deg) ? beg + j + 1 : 0;
        int i2 = (j + 2 < deg) ? beg + j + 2 : 0;
        int i3 = (j + 3 < deg) ? beg + j + 3 : 0;
        int s0 = src[i0], s1 = src[i1], s2 = src[i2], s3 = src[i3];
        float w0 = (j + 0 < deg) ? dinv[s0] : 0.f;
        float w1 = (j + 1 < deg) ? dinv[s1] : 0.f;
        float w2 = (j + 2 < deg) ? dinv[s2] : 0.f;
        float w3 = (j + 3 < deg) ? dinv[s3] : 0.f;
        float4 v0 = *(const float4*)&h[(size_t)s0 * 128 + c4];
        float4 v1 = *(const float4*)&h[(size_t)s1 * 128 + c4];
        float4 v2 = *(const float4*)&h[(size_t)s2 * 128 + c4];
        float4 v3 = *(const float4*)&h[(size_t)s3 * 128 + c4];
        acc.x = fmaf(w0, v0.x, fmaf(w1, v1.x, fmaf(w2, v2.x, fmaf(w3, v3.x, acc.x))));
        acc.y = fmaf(w0, v0.y, fmaf(w1, v1.y, fmaf(w2, v2.y, fmaf(w3, v3.y, acc.y))));
        acc.z = fmaf(w0, v0.z, fmaf(w1, v1.z, fmaf(w2, v2.z, fmaf(w3, v3.z, acc.z))));
        acc.w = fmaf(w0, v0.w, fmaf(w1, v1.w, fmaf(w2, v2.w, fmaf(w3, v3.w, acc.w))));
    }
    float4 b = *(const float4*)&bias[c4];
    float4 o;
    o.x = fmaxf(fmaf(dc, acc.x, b.x), 0.f);
    o.y = fmaxf(fmaf(dc, acc.y, b.y), 0.f);
    o.z = fmaxf(fmaf(dc, acc.z, b.z), 0.f);
    o.w = fmaxf(fmaf(dc, acc.w, b.w), 0.f);
    if (node < N_NODES) *(float4*)&out[(size_t)node * 128 + c4] = o;
}

// ---------------------------------------------------------------------------
// K6: SAGE mean aggregation, same 2-node/wave float4 structure.
// ---------------------------------------------------------------------------
__global__ __launch_bounds__(256) void sage_agg_k(const float* __restrict__ hg,
                                                  const int* __restrict__ offs,
                                                  const int* __restrict__ src,
                                                  float* __restrict__ out) {
    const int wave = threadIdx.x >> 6;
    const int lane = threadIdx.x & 63;
    const int half = lane >> 5;
    const int node = (blockIdx.x * 4 + wave) * 2 + half;
    const int c4 = (lane & 31) * 4;
    const int nd = (node < N_NODES) ? node : (N_NODES - 1);
    float4 acc = make_float4(0.f, 0.f, 0.f, 0.f);
    const int beg = offs[nd];
    const int deg = offs[nd + 1] - beg;
    const int mdeg = max(deg, __shfl(deg, lane ^ 32));
    for (int j = 0; j < mdeg; j += 4) {
        int i0 = (j + 0 < deg) ? beg + j + 0 : 0;
        int i1 = (j + 1 < deg) ? beg + j + 1 : 0;
        int i2 = (j + 2 < deg) ? beg + j + 2 : 0;
        int i3 = (j + 3 < deg) ? beg + j + 3 : 0;
        float w0 = (j + 0 < deg) ? 1.f : 0.f;
        float w1 = (j + 1 < deg) ? 1.f : 0.f;
        float w2 = (j + 2 < deg) ? 1.f : 0.f;
        float w3 = (j + 3 < deg) ? 1.f : 0.f;
        int s0 = src[i0], s1 = src[i1], s2 = src[i2], s3 = src[i3];
        float4 v0 = *(const float4*)&hg[(size_t)s0 * 128 + c4];
        float4 v1 = *(const float4*)&hg[(size_t)s1 * 128 + c4];
        float4 v2 = *(const float4*)&hg[(size_t)s2 * 128 + c4];
        float4 v3 = *(const float4*)&hg[(size_t)s3 * 128 + c4];
        acc.x = fmaf(w0, v0.x, fmaf(w1, v1.x, fmaf(w2, v2.x, fmaf(w3, v3.x, acc.x))));
        acc.y = fmaf(w0, v0.y, fmaf(w1, v1.y, fmaf(w2, v2.y, fmaf(w3, v3.y, acc.y))));
        acc.z = fmaf(w0, v0.z, fmaf(w1, v1.z, fmaf(w2, v2.z, fmaf(w3, v3.z, acc.z))));
        acc.w = fmaf(w0, v0.w, fmaf(w1, v1.w, fmaf(w2, v2.w, fmaf(w3, v3.w, acc.w))));
    }
    float inv = 1.0f / (float)max(deg, 1);
    float4 o;
    o.x = acc.x * inv;
    o.y = acc.y * inv;
    o.z = acc.z * inv;
    o.w = acc.w * inv;
    if (node < N_NODES) *(float4*)&out[(size_t)node * 128 + c4] = o;
}

// ---------------------------------------------------------------------------
// K7: h_sage = relu(neigh @ Wl + h_gcn @ Wr + b). Same scalar-x structure as
// gemm128_k; W chunks staged 4x (2 matrices x 2 halves). In-place safe:
// each block's rows read only by itself, all reads precede writes.
// ---------------------------------------------------------------------------
__global__ __launch_bounds__(256) void combine_k(const float* __restrict__ An,
                                                 const float* __restrict__ Bh,
                                                 const float* __restrict__ Wl,
                                                 const float* __restrict__ Wr,
                                                 const float* __restrict__ bias,
                                                 float* __restrict__ Y) {
    __shared__ float wbuf[64 * 128];  // 32 KB
    const int t = threadIdx.x;
    const int lane = t & 63;
    const int wid = __builtin_amdgcn_readfirstlane(t >> 6);
    const int c2 = lane * 2;
    const int row0 = blockIdx.x * 32 + wid * 8;
    float2 acc[8];
    {
        float2 b = *(const float2*)&bias[c2];
#pragma unroll
        for (int r = 0; r < 8; ++r) acc[r] = b;
    }
#pragma unroll
    for (int m = 0; m < 2; ++m) {
        const float* Wm = m ? Wr : Wl;
        const float* Xr = (m ? Bh : An) + (size_t)row0 * 128;
#pragma unroll
        for (int kc = 0; kc < 2; ++kc) {
            __syncthreads();
#pragma unroll
            for (int i = 0; i < 8; ++i)
                ((float4*)wbuf)[t + i * 256] = ((const float4*)Wm)[kc * 2048 + t + i * 256];
            __syncthreads();
            const int kb = kc * 64;
            for (int k0 = 0; k0 < 64; k0 += 4) {
                float4 xa[8];
#pragma unroll
                for (int r = 0; r < 8; ++r)
                    xa[r] = *(const float4*)&Xr[r * 128 + kb + k0];
#pragma unroll
                for (int kk = 0; kk < 4; ++kk) {
                    float2 w = *(const float2*)&wbuf[(k0 + kk) * 128 + c2];
#pragma unroll
                    for (int r = 0; r < 8; ++r) {
                        float xv = (&xa[r].x)[kk];
                        acc[r].x = fmaf(xv, w.x, acc[r].x);
                        acc[r].y = fmaf(xv, w.y, acc[r].y);
                    }
                }
            }
        }
    }
#pragma unroll
    for (int r = 0; r < 8; ++r) {
        float2 o = acc[r];
        o.x = fmaxf(o.x, 0.f);
        o.y = fmaxf(o.y, 0.f);
        *(float2*)&Y[(size_t)(row0 + r) * 128 + c2] = o;
    }
}

// ---------------------------------------------------------------------------
// K8a: global_add_pool, parallel. Per-thread segmented sum over sorted batch,
// one atomicAdd per (thread, graph-segment).
// ---------------------------------------------------------------------------
#define POOL_ROWS 64
__global__ __launch_bounds__(256) void pool_k(const float* __restrict__ H,
                                              const int* __restrict__ batch,
                                              float* __restrict__ pooled) {
    const int r0 = blockIdx.x * POOL_ROWS;
    const int t = threadIdx.x;
    const int d = t & 127, half = t >> 7;
    const int rend = min(r0 + POOL_ROWS, N_NODES);
    int i = r0 + half;
    if (i >= rend) return;
    int cur = batch[i];
    float acc = 0.f;
    for (; i < rend; i += 2) {
        int g = batch[i];
        if (g != cur) {
            atomicAdd(&pooled[cur * 128 + d], acc);
            acc = 0.f;
            cur = g;
        }
        acc += H[(size_t)i * 128 + d];
    }
    atomicAdd(&pooled[cur * 128 + d], acc);
}

// ---------------------------------------------------------------------------
// K8b: MLP head. One block per graph, 128 threads.
// ---------------------------------------------------------------------------
__global__ __launch_bounds__(128) void head_k(const float* __restrict__ pooled,
                                              const float* __restrict__ Wfc1,
                                              const float* __restrict__ bfc1,
                                              const float* __restrict__ Wfc2,
                                              const float* __restrict__ bfc2,
                                              float* __restrict__ out) {
    __shared__ float pl[128];
    __shared__ float tmp[128];
    const int g = blockIdx.x;
    const int t = threadIdx.x;
    pl[t] = pooled[g * 128 + t];
    __syncthreads();
    float a = bfc1[t];
#pragma unroll 8
    for (int k = 0; k < 128; ++k) a = fmaf(pl[k], Wfc1[k * 128 + t], a);
    tmp[t] = fmaxf(a, 0.f);
    __syncthreads();
    if (t < 3) {
        float a2 = bfc2[t];
        for (int k = 0; k < 128; ++k) a2 = fmaf(tmp[k], Wfc2[k * 3 + t], a2);
        out[g * 3 + t] = a2;
    }
}

// ---------------------------------------------------------------------------
extern "C" void kernel_launch(void* const* d_in, const int* in_sizes, int n_in,
                              void* d_out, int out_size, void* d_ws, size_t ws_size,
                              hipStream_t stream) {
    const float* x      = (const float*)d_in[0];
    const int*   ei     = (const int*)d_in[1];   // [2, E]: row = ei, col = ei+E
    const int*   batch  = (const int*)d_in[2];
    const float* W_gcn  = (const float*)d_in[3];
    const float* b_gcn  = (const float*)d_in[4];
    const float* W_sl   = (const float*)d_in[5];
    const float* W_sr   = (const float*)d_in[6];
    const float* b_sage = (const float*)d_in[7];
    const float* W_fc1  = (const float*)d_in[8];
    const float* b_fc1  = (const float*)d_in[9];
    const float* W_fc2  = (const float*)d_in[10];
    const float* b_fc2  = (const float*)d_in[11];
    float* out = (float*)d_out;

    char* base = (char*)d_ws;
    size_t off = 0;
    auto take = [&](size_t bytes) -> void* {
        void* p = base + off;
        off += (bytes + 255) & ~(size_t)255;
        return p;
    };
    int*   cnt      = (int*)take((size_t)N_NODES * 4);
    int*   offs     = (int*)take((size_t)(N_NODES + 1) * 4);
    int*   cursor   = (int*)take((size_t)N_NODES * 4);
    float* dinv     = (float*)take((size_t)N_NODES * 4);
    int*   blkSum   = (int*)take((size_t)SCAN_NBLK * 4);
    int*   csr_src  = (int*)take((size_t)N_EDGES * 4);
    float* bufA     = (float*)take((size_t)N_NODES * HID * 4);  // h -> neigh -> h_sage
    float* bufB     = (float*)take((size_t)N_NODES * HID * 4);  // h_gcn
    float* pooled   = (float*)take((size_t)N_GRAPHS * HID * 4);

    const int* row = ei;
    const int* col = ei + N_EDGES;

    hipMemsetAsync(cnt, 0, (size_t)N_NODES * 4, stream);
    hipMemsetAsync(pooled, 0, (size_t)N_GRAPHS * HID * 4, stream);

    hist_k<<<(N_EDGES + 255) / 256, 256, 0, stream>>>(col, cnt);
    scanA_k<<<SCAN_NBLK, SCAN_BLK, 0, stream>>>(cnt, blkSum);
    scanB_k<<<SCAN_NBLK, SCAN_BLK, 0, stream>>>(cnt, blkSum, offs, cursor, dinv);
    fill_k<<<(N_EDGES + 255) / 256, 256, 0, stream>>>(row, col, cursor, csr_src);

    const int gemm_blocks = N_NODES / 32;     // 625 (exact)
    const int agg_blocks = (N_NODES + 7) / 8; // 2500 (8 nodes per block)
    // h = x @ W_gcn
    gemm128_k<<<gemm_blocks, 256, 0, stream>>>(x, W_gcn, bufA);
    // h_gcn = relu(aggregate(h) + b_gcn)
    gcn_agg_k<<<agg_blocks, 256, 0, stream>>>(bufA, offs, csr_src, dinv, b_gcn, bufB);
    // neigh = mean-aggregate(h_gcn)   (bufA reused; h is dead)
    sage_agg_k<<<agg_blocks, 256, 0, stream>>>(bufB, offs, csr_src, bufA);
    // h_sage = relu(neigh @ Wl + h_gcn @ Wr + b)   (in-place over bufA)
    combine_k<<<gemm_blocks, 256, 0, stream>>>(bufA, bufB, W_sl, W_sr, b_sage, bufA);
    // pooled (atomic segmented sum) + MLP head
    pool_k<<<(N_NODES + POOL_ROWS - 1) / POOL_ROWS, 256, 0, stream>>>(bufA, batch, pooled);
    head_k<<<N_GRAPHS, 128, 0, stream>>>(pooled, W_fc1, b_fc1, W_fc2, b_fc2, out);
}

// Round 12
// 300.147 us; speedup vs baseline: 1.0995x; 1.0995x over previous
//
#include <hip/hip_runtime.h>

#define N_NODES 20000
#define N_EDGES 640000
#define HID 128
#define N_GRAPHS 32

#define SCAN_BLK 256
#define SCAN_NBLK ((N_NODES + SCAN_BLK - 1) / SCAN_BLK)  // 79

#define XT_STRIDE 36  // padded: 36*4=144 B row stride (16B-aligned, bank-spread)

// ---------------------------------------------------------------------------
// K1: in-degree histogram over target nodes (col)
// ---------------------------------------------------------------------------
__global__ __launch_bounds__(256) void hist_k(const int* __restrict__ col,
                                              int* __restrict__ cnt) {
    int e = blockIdx.x * blockDim.x + threadIdx.x;
    if (e < N_EDGES) {
        int c = col[e];
        if ((unsigned)c < N_NODES) atomicAdd(&cnt[c], 1);
    }
}

// ---------------------------------------------------------------------------
// K2a: per-block sums of cnt (coalesced), 79 blocks x 256 thr
// ---------------------------------------------------------------------------
__global__ __launch_bounds__(SCAN_BLK) void scanA_k(const int* __restrict__ cnt,
                                                    int* __restrict__ blkSum) {
    __shared__ int wsum[SCAN_BLK / 64];
    const int b = blockIdx.x, t = threadIdx.x;
    const int i = b * SCAN_BLK + t;
    int v = (i < N_NODES) ? cnt[i] : 0;
#pragma unroll
    for (int o = 1; o < 64; o <<= 1) v += __shfl_xor(v, o);
    if ((t & 63) == 0) wsum[t >> 6] = v;
    __syncthreads();
    if (t == 0) {
        int s = 0;
#pragma unroll
        for (int w = 0; w < SCAN_BLK / 64; ++w) s += wsum[w];
        blkSum[b] = s;
    }
}

// ---------------------------------------------------------------------------
// K2b: per-block exclusive scan + block base from blkSum. Coalesced writes of
// offs/cursor/dinv. Thread owning node N-1 writes offs[N_NODES].
// ---------------------------------------------------------------------------
__global__ __launch_bounds__(SCAN_BLK) void scanB_k(const int* __restrict__ cnt,
                                                    const int* __restrict__ blkSum,
                                                    int* __restrict__ offs,
                                                    int* __restrict__ cursor,
                                                    float* __restrict__ dinv) {
    __shared__ int sm[SCAN_BLK];
    __shared__ int base_s;
    const int b = blockIdx.x, t = threadIdx.x;
    const int i = b * SCAN_BLK + t;
    const int v = (i < N_NODES) ? cnt[i] : 0;
    sm[t] = v;
    if (t == 0) {
        int s = 0;
        for (int k = 0; k < b; ++k) s += blkSum[k];
        base_s = s;
    }
    __syncthreads();
    // Hillis-Steele inclusive scan over 256 entries (8 rounds)
    for (int o = 1; o < SCAN_BLK; o <<= 1) {
        int add = (t >= o) ? sm[t - o] : 0;
        __syncthreads();
        sm[t] += add;
        __syncthreads();
    }
    if (i < N_NODES) {
        int excl = base_s + ((t > 0) ? sm[t - 1] : 0);
        offs[i] = excl;
        cursor[i] = excl;
        dinv[i] = rsqrtf((float)(v + 1));  // self-loop included, deg>=1 always
        if (i == N_NODES - 1) offs[N_NODES] = excl + v;
    }
}

// ---------------------------------------------------------------------------
// K3: CSR fill, src index ONLY (norm reconstructed in agg via dinv[src]).
// ---------------------------------------------------------------------------
__global__ __launch_bounds__(256) void fill_k(const int* __restrict__ row,
                                              const int* __restrict__ col,
                                              int* __restrict__ cursor,
                                              int* __restrict__ csr_src) {
    int e = blockIdx.x * blockDim.x + threadIdx.x;
    if (e < N_EDGES) {
        int c = col[e];
        int r = row[e];
        if ((unsigned)c < N_NODES && (unsigned)r < N_NODES) {
            int p = atomicAdd(&cursor[c], 1);
            csr_src[p] = r;
        }
    }
}

// ---------------------------------------------------------------------------
// Shared GEMM helpers: 32-row tile, 4r x 4c per thread.
// xT staged transposed in LDS ([128][36] padded): per-k read is ONE b128
// broadcast (rows) + ONE b128 W (cols) per lane -> ~1 B per fmaf-lane.
// W staged in 32 KB k-halves. LDS total 50.25 KB -> 3 blocks/CU.
// ---------------------------------------------------------------------------
__device__ __forceinline__ void stage_xt(float* xt, const float* __restrict__ Xm,
                                         int row0, int t) {
    const int r = t & 31;
    const int kbase = (t >> 5) * 16;
    const float* xp = Xm + (size_t)(row0 + r) * 128 + kbase;
#pragma unroll
    for (int c = 0; c < 4; ++c) {
        float4 v = *(const float4*)&xp[c * 4];
        xt[(kbase + c * 4 + 0) * XT_STRIDE + r] = v.x;
        xt[(kbase + c * 4 + 1) * XT_STRIDE + r] = v.y;
        xt[(kbase + c * 4 + 2) * XT_STRIDE + r] = v.z;
        xt[(kbase + c * 4 + 3) * XT_STRIDE + r] = v.w;
    }
}

__device__ __forceinline__ void gemm_half(const float* xt, const float* wbuf,
                                          int kb, int rg, int c4, float4 acc[4]) {
#pragma unroll 8
    for (int k0 = 0; k0 < 64; ++k0) {
        float4 w = *(const float4*)&wbuf[k0 * 128 + c4];
        float4 xr = *(const float4*)&xt[(kb + k0) * XT_STRIDE + rg * 4];
        acc[0].x = fmaf(xr.x, w.x, acc[0].x);
        acc[0].y = fmaf(xr.x, w.y, acc[0].y);
        acc[0].z = fmaf(xr.x, w.z, acc[0].z);
        acc[0].w = fmaf(xr.x, w.w, acc[0].w);
        acc[1].x = fmaf(xr.y, w.x, acc[1].x);
        acc[1].y = fmaf(xr.y, w.y, acc[1].y);
        acc[1].z = fmaf(xr.y, w.z, acc[1].z);
        acc[1].w = fmaf(xr.y, w.w, acc[1].w);
        acc[2].x = fmaf(xr.z, w.x, acc[2].x);
        acc[2].y = fmaf(xr.z, w.y, acc[2].y);
        acc[2].z = fmaf(xr.z, w.z, acc[2].z);
        acc[2].w = fmaf(xr.z, w.w, acc[2].w);
        acc[3].x = fmaf(xr.w, w.x, acc[3].x);
        acc[3].y = fmaf(xr.w, w.y, acc[3].y);
        acc[3].z = fmaf(xr.w, w.z, acc[3].z);
        acc[3].w = fmaf(xr.w, w.w, acc[3].w);
    }
}

// ---------------------------------------------------------------------------
// K4: Y[20000,128] = X @ W (f32).
// ---------------------------------------------------------------------------
__global__ __launch_bounds__(256) void gemm128_k(const float* __restrict__ X,
                                                 const float* __restrict__ W,
                                                 float* __restrict__ Y) {
    __shared__ float wbuf[64 * 128];           // 32 KB
    __shared__ float xt[128 * XT_STRIDE];      // 18 KB (transposed x tile)
    const int t = threadIdx.x;
    const int rg = t >> 5;         // 0..7 -> rows rg*4..+3
    const int c4 = (t & 31) * 4;   // cols
    const int row0 = blockIdx.x * 32;
    float4 acc[4];
    acc[0] = acc[1] = acc[2] = acc[3] = make_float4(0.f, 0.f, 0.f, 0.f);
    stage_xt(xt, X, row0, t);
#pragma unroll
    for (int kc = 0; kc < 2; ++kc) {
        if (kc) __syncthreads();  // protect wbuf before restage
#pragma unroll
        for (int i = 0; i < 8; ++i)
            ((float4*)wbuf)[t + i * 256] = ((const float4*)W)[kc * 2048 + t + i * 256];
        __syncthreads();
        gemm_half(xt, wbuf, kc * 64, rg, c4, acc);
    }
#pragma unroll
    for (int i = 0; i < 4; ++i)
        *(float4*)&Y[(size_t)(row0 + rg * 4 + i) * 128 + c4] = acc[i];
}

// ---------------------------------------------------------------------------
// K5: GCN aggregation. TWO nodes per wave, float4/lane.
// Edge weight = dinv[src] (broadcast). OOB edge -> index 0, weight 0.
// out[c] = relu(dinv[c]*(sum_j dinv[src_j]*h[src_j] + dinv[c]*h[c]) + bias)
// ---------------------------------------------------------------------------
__global__ __launch_bounds__(256) void gcn_agg_k(const float* __restrict__ h,
                                                 const int* __restrict__ offs,
                                                 const int* __restrict__ src,
                                                 const float* __restrict__ dinv,
                                                 const float* __restrict__ bias,
                                                 float* __restrict__ out) {
    const int wave = threadIdx.x >> 6;
    const int lane = threadIdx.x & 63;
    const int half = lane >> 5;
    const int node = (blockIdx.x * 4 + wave) * 2 + half;
    const int c4 = (lane & 31) * 4;
    const int nd = (node < N_NODES) ? node : (N_NODES - 1);
    const float dc = dinv[nd];
    float4 hv = *(const float4*)&h[(size_t)nd * 128 + c4];
    float4 acc = make_float4(dc * hv.x, dc * hv.y, dc * hv.z, dc * hv.w);
    const int beg = offs[nd];
    const int deg = offs[nd + 1] - beg;
    const int mdeg = max(deg, __shfl(deg, lane ^ 32));
    for (int j = 0; j < mdeg; j += 4) {
        int i0 = (j + 0 < deg) ? beg + j + 0 : 0;
        int i1 = (j + 1 < deg) ? beg + j + 1 : 0;
        int i2 = (j + 2 < deg) ? beg + j + 2 : 0;
        int i3 = (j + 3 < deg) ? beg + j + 3 : 0;
        int s0 = src[i0], s1 = src[i1], s2 = src[i2], s3 = src[i3];
        float w0 = (j + 0 < deg) ? dinv[s0] : 0.f;
        float w1 = (j + 1 < deg) ? dinv[s1] : 0.f;
        float w2 = (j + 2 < deg) ? dinv[s2] : 0.f;
        float w3 = (j + 3 < deg) ? dinv[s3] : 0.f;
        float4 v0 = *(const float4*)&h[(size_t)s0 * 128 + c4];
        float4 v1 = *(const float4*)&h[(size_t)s1 * 128 + c4];
        float4 v2 = *(const float4*)&h[(size_t)s2 * 128 + c4];
        float4 v3 = *(const float4*)&h[(size_t)s3 * 128 + c4];
        acc.x = fmaf(w0, v0.x, fmaf(w1, v1.x, fmaf(w2, v2.x, fmaf(w3, v3.x, acc.x))));
        acc.y = fmaf(w0, v0.y, fmaf(w1, v1.y, fmaf(w2, v2.y, fmaf(w3, v3.y, acc.y))));
        acc.z = fmaf(w0, v0.z, fmaf(w1, v1.z, fmaf(w2, v2.z, fmaf(w3, v3.z, acc.z))));
        acc.w = fmaf(w0, v0.w, fmaf(w1, v1.w, fmaf(w2, v2.w, fmaf(w3, v3.w, acc.w))));
    }
    float4 b = *(const float4*)&bias[c4];
    float4 o;
    o.x = fmaxf(fmaf(dc, acc.x, b.x), 0.f);
    o.y = fmaxf(fmaf(dc, acc.y, b.y), 0.f);
    o.z = fmaxf(fmaf(dc, acc.z, b.z), 0.f);
    o.w = fmaxf(fmaf(dc, acc.w, b.w), 0.f);
    if (node < N_NODES) *(float4*)&out[(size_t)node * 128 + c4] = o;
}

// ---------------------------------------------------------------------------
// K6: SAGE mean aggregation, same 2-node/wave float4 structure.
// ---------------------------------------------------------------------------
__global__ __launch_bounds__(256) void sage_agg_k(const float* __restrict__ hg,
                                                  const int* __restrict__ offs,
                                                  const int* __restrict__ src,
                                                  float* __restrict__ out) {
    const int wave = threadIdx.x >> 6;
    const int lane = threadIdx.x & 63;
    const int half = lane >> 5;
    const int node = (blockIdx.x * 4 + wave) * 2 + half;
    const int c4 = (lane & 31) * 4;
    const int nd = (node < N_NODES) ? node : (N_NODES - 1);
    float4 acc = make_float4(0.f, 0.f, 0.f, 0.f);
    const int beg = offs[nd];
    const int deg = offs[nd + 1] - beg;
    const int mdeg = max(deg, __shfl(deg, lane ^ 32));
    for (int j = 0; j < mdeg; j += 4) {
        int i0 = (j + 0 < deg) ? beg + j + 0 : 0;
        int i1 = (j + 1 < deg) ? beg + j + 1 : 0;
        int i2 = (j + 2 < deg) ? beg + j + 2 : 0;
        int i3 = (j + 3 < deg) ? beg + j + 3 : 0;
        float w0 = (j + 0 < deg) ? 1.f : 0.f;
        float w1 = (j + 1 < deg) ? 1.f : 0.f;
        float w2 = (j + 2 < deg) ? 1.f : 0.f;
        float w3 = (j + 3 < deg) ? 1.f : 0.f;
        int s0 = src[i0], s1 = src[i1], s2 = src[i2], s3 = src[i3];
        float4 v0 = *(const float4*)&hg[(size_t)s0 * 128 + c4];
        float4 v1 = *(const float4*)&hg[(size_t)s1 * 128 + c4];
        float4 v2 = *(const float4*)&hg[(size_t)s2 * 128 + c4];
        float4 v3 = *(const float4*)&hg[(size_t)s3 * 128 + c4];
        acc.x = fmaf(w0, v0.x, fmaf(w1, v1.x, fmaf(w2, v2.x, fmaf(w3, v3.x, acc.x))));
        acc.y = fmaf(w0, v0.y, fmaf(w1, v1.y, fmaf(w2, v2.y, fmaf(w3, v3.y, acc.y))));
        acc.z = fmaf(w0, v0.z, fmaf(w1, v1.z, fmaf(w2, v2.z, fmaf(w3, v3.z, acc.z))));
        acc.w = fmaf(w0, v0.w, fmaf(w1, v1.w, fmaf(w2, v2.w, fmaf(w3, v3.w, acc.w))));
    }
    float inv = 1.0f / (float)max(deg, 1);
    float4 o;
    o.x = acc.x * inv;
    o.y = acc.y * inv;
    o.z = acc.z * inv;
    o.w = acc.w * inv;
    if (node < N_NODES) *(float4*)&out[(size_t)node * 128 + c4] = o;
}

// ---------------------------------------------------------------------------
// K7: h_sage = relu(neigh @ Wl + h_gcn @ Wr + b). In-place over neigh (bufA):
// all An reads complete (m=0) before the epilogue write; rows are block-private.
// ---------------------------------------------------------------------------
__global__ __launch_bounds__(256) void combine_k(const float* __restrict__ An,
                                                 const float* __restrict__ Bh,
                                                 const float* __restrict__ Wl,
                                                 const float* __restrict__ Wr,
                                                 const float* __restrict__ bias,
                                                 float* __restrict__ Y) {
    __shared__ float wbuf[64 * 128];           // 32 KB
    __shared__ float xt[128 * XT_STRIDE];      // 18 KB
    const int t = threadIdx.x;
    const int rg = t >> 5;
    const int c4 = (t & 31) * 4;
    const int row0 = blockIdx.x * 32;
    float4 acc[4];
    {
        float4 b = *(const float4*)&bias[c4];
        acc[0] = acc[1] = acc[2] = acc[3] = b;
    }
#pragma unroll
    for (int m = 0; m < 2; ++m) {
        const float* Wm = m ? Wr : Wl;
        const float* Xm = m ? Bh : An;
        if (m) __syncthreads();  // protect xt before restage
        stage_xt(xt, Xm, row0, t);
#pragma unroll
        for (int kc = 0; kc < 2; ++kc) {
            if (m || kc) __syncthreads();  // protect wbuf before restage
#pragma unroll
            for (int i = 0; i < 8; ++i)
                ((float4*)wbuf)[t + i * 256] = ((const float4*)Wm)[kc * 2048 + t + i * 256];
            __syncthreads();
            gemm_half(xt, wbuf, kc * 64, rg, c4, acc);
        }
    }
#pragma unroll
    for (int i = 0; i < 4; ++i) {
        float4 o = acc[i];
        o.x = fmaxf(o.x, 0.f);
        o.y = fmaxf(o.y, 0.f);
        o.z = fmaxf(o.z, 0.f);
        o.w = fmaxf(o.w, 0.f);
        *(float4*)&Y[(size_t)(row0 + rg * 4 + i) * 128 + c4] = o;
    }
}

// ---------------------------------------------------------------------------
// K8a: global_add_pool, parallel. Per-thread segmented sum over sorted batch,
// one atomicAdd per (thread, graph-segment).
// ---------------------------------------------------------------------------
#define POOL_ROWS 64
__global__ __launch_bounds__(256) void pool_k(const float* __restrict__ H,
                                              const int* __restrict__ batch,
                                              float* __restrict__ pooled) {
    const int r0 = blockIdx.x * POOL_ROWS;
    const int t = threadIdx.x;
    const int d = t & 127, half = t >> 7;
    const int rend = min(r0 + POOL_ROWS, N_NODES);
    int i = r0 + half;
    if (i >= rend) return;
    int cur = batch[i];
    float acc = 0.f;
    for (; i < rend; i += 2) {
        int g = batch[i];
        if (g != cur) {
            atomicAdd(&pooled[cur * 128 + d], acc);
            acc = 0.f;
            cur = g;
        }
        acc += H[(size_t)i * 128 + d];
    }
    atomicAdd(&pooled[cur * 128 + d], acc);
}

// ---------------------------------------------------------------------------
// K8b: MLP head. One block per graph, 128 threads.
// ---------------------------------------------------------------------------
__global__ __launch_bounds__(128) void head_k(const float* __restrict__ pooled,
                                              const float* __restrict__ Wfc1,
                                              const float* __restrict__ bfc1,
                                              const float* __restrict__ Wfc2,
                                              const float* __restrict__ bfc2,
                                              float* __restrict__ out) {
    __shared__ float pl[128];
    __shared__ float tmp[128];
    const int g = blockIdx.x;
    const int t = threadIdx.x;
    pl[t] = pooled[g * 128 + t];
    __syncthreads();
    float a = bfc1[t];
#pragma unroll 8
    for (int k = 0; k < 128; ++k) a = fmaf(pl[k], Wfc1[k * 128 + t], a);
    tmp[t] = fmaxf(a, 0.f);
    __syncthreads();
    if (t < 3) {
        float a2 = bfc2[t];
        for (int k = 0; k < 128; ++k) a2 = fmaf(tmp[k], Wfc2[k * 3 + t], a2);
        out[g * 3 + t] = a2;
    }
}

// ---------------------------------------------------------------------------
extern "C" void kernel_launch(void* const* d_in, const int* in_sizes, int n_in,
                              void* d_out, int out_size, void* d_ws, size_t ws_size,
                              hipStream_t stream) {
    const float* x      = (const float*)d_in[0];
    const int*   ei     = (const int*)d_in[1];   // [2, E]: row = ei, col = ei+E
    const int*   batch  = (const int*)d_in[2];
    const float* W_gcn  = (const float*)d_in[3];
    const float* b_gcn  = (const float*)d_in[4];
    const float* W_sl   = (const float*)d_in[5];
    const float* W_sr   = (const float*)d_in[6];
    const float* b_sage = (const float*)d_in[7];
    const float* W_fc1  = (const float*)d_in[8];
    const float* b_fc1  = (const float*)d_in[9];
    const float* W_fc2  = (const float*)d_in[10];
    const float* b_fc2  = (const float*)d_in[11];
    float* out = (float*)d_out;

    char* base = (char*)d_ws;
    size_t off = 0;
    auto take = [&](size_t bytes) -> void* {
        void* p = base + off;
        off += (bytes + 255) & ~(size_t)255;
        return p;
    };
    int*   cnt      = (int*)take((size_t)N_NODES * 4);
    int*   offs     = (int*)take((size_t)(N_NODES + 1) * 4);
    int*   cursor   = (int*)take((size_t)N_NODES * 4);
    float* dinv     = (float*)take((size_t)N_NODES * 4);
    int*   blkSum   = (int*)take((size_t)SCAN_NBLK * 4);
    int*   csr_src  = (int*)take((size_t)N_EDGES * 4);
    float* bufA     = (float*)take((size_t)N_NODES * HID * 4);  // h -> neigh -> h_sage
    float* bufB     = (float*)take((size_t)N_NODES * HID * 4);  // h_gcn
    float* pooled   = (float*)take((size_t)N_GRAPHS * HID * 4);

    const int* row = ei;
    const int* col = ei + N_EDGES;

    hipMemsetAsync(cnt, 0, (size_t)N_NODES * 4, stream);
    hipMemsetAsync(pooled, 0, (size_t)N_GRAPHS * HID * 4, stream);

    hist_k<<<(N_EDGES + 255) / 256, 256, 0, stream>>>(col, cnt);
    scanA_k<<<SCAN_NBLK, SCAN_BLK, 0, stream>>>(cnt, blkSum);
    scanB_k<<<SCAN_NBLK, SCAN_BLK, 0, stream>>>(cnt, blkSum, offs, cursor, dinv);
    fill_k<<<(N_EDGES + 255) / 256, 256, 0, stream>>>(row, col, cursor, csr_src);

    const int gemm_blocks = N_NODES / 32;     // 625 (exact)
    const int agg_blocks = (N_NODES + 7) / 8; // 2500 (8 nodes per block)
    // h = x @ W_gcn
    gemm128_k<<<gemm_blocks, 256, 0, stream>>>(x, W_gcn, bufA);
    // h_gcn = relu(aggregate(h) + b_gcn)
    gcn_agg_k<<<agg_blocks, 256, 0, stream>>>(bufA, offs, csr_src, dinv, b_gcn, bufB);
    // neigh = mean-aggregate(h_gcn)   (bufA reused; h is dead)
    sage_agg_k<<<agg_blocks, 256, 0, stream>>>(bufB, offs, csr_src, bufA);
    // h_sage = relu(neigh @ Wl + h_gcn @ Wr + b)   (in-place over bufA)
    combine_k<<<gemm_blocks, 256, 0, stream>>>(bufA, bufB, W_sl, W_sr, b_sage, bufA);
    // pooled (atomic segmented sum) + MLP head
    pool_k<<<(N_NODES + POOL_ROWS - 1) / POOL_ROWS, 256, 0, stream>>>(bufA, batch, pooled);
    head_k<<<N_GRAPHS, 128, 0, stream>>>(pooled, W_fc1, b_fc1, W_fc2, b_fc2, out);
}

// Round 13
// 294.464 us; speedup vs baseline: 1.1207x; 1.0193x over previous
//
#include <hip/hip_runtime.h>

#define N_NODES 20000
#define N_EDGES 640000
#define HID 128
#define N_GRAPHS 32

#define SCAN_BLK 256
#define SCAN_NBLK ((N_NODES + SCAN_BLK - 1) / SCAN_BLK)  // 79

#define XT_STRIDE 36  // padded: 36*4=144 B row stride (16B-aligned, bank-spread)

// ---------------------------------------------------------------------------
// K1: in-degree histogram over target nodes (col)
// ---------------------------------------------------------------------------
__global__ __launch_bounds__(256) void hist_k(const int* __restrict__ col,
                                              int* __restrict__ cnt) {
    int e = blockIdx.x * blockDim.x + threadIdx.x;
    if (e < N_EDGES) {
        int c = col[e];
        if ((unsigned)c < N_NODES) atomicAdd(&cnt[c], 1);
    }
}

// ---------------------------------------------------------------------------
// K2a: per-block sums of cnt (coalesced), 79 blocks x 256 thr
// ---------------------------------------------------------------------------
__global__ __launch_bounds__(SCAN_BLK) void scanA_k(const int* __restrict__ cnt,
                                                    int* __restrict__ blkSum) {
    __shared__ int wsum[SCAN_BLK / 64];
    const int b = blockIdx.x, t = threadIdx.x;
    const int i = b * SCAN_BLK + t;
    int v = (i < N_NODES) ? cnt[i] : 0;
#pragma unroll
    for (int o = 1; o < 64; o <<= 1) v += __shfl_xor(v, o);
    if ((t & 63) == 0) wsum[t >> 6] = v;
    __syncthreads();
    if (t == 0) {
        int s = 0;
#pragma unroll
        for (int w = 0; w < SCAN_BLK / 64; ++w) s += wsum[w];
        blkSum[b] = s;
    }
}

// ---------------------------------------------------------------------------
// K2b: per-block exclusive scan + block base from blkSum. Coalesced writes of
// offs/cursor/dinv. Block 0 also zeroes the pooled buffer (replaces a memset
// dispatch; runs well before pool_k in the same stream).
// ---------------------------------------------------------------------------
__global__ __launch_bounds__(SCAN_BLK) void scanB_k(const int* __restrict__ cnt,
                                                    const int* __restrict__ blkSum,
                                                    int* __restrict__ offs,
                                                    int* __restrict__ cursor,
                                                    float* __restrict__ dinv,
                                                    float* __restrict__ pooled) {
    __shared__ int sm[SCAN_BLK];
    __shared__ int base_s;
    const int b = blockIdx.x, t = threadIdx.x;
    const int i = b * SCAN_BLK + t;
    const int v = (i < N_NODES) ? cnt[i] : 0;
    sm[t] = v;
    if (b == 0) {
#pragma unroll
        for (int j = 0; j < (N_GRAPHS * HID) / SCAN_BLK; ++j)
            pooled[j * SCAN_BLK + t] = 0.f;
    }
    if (t == 0) {
        int s = 0;
        for (int k = 0; k < b; ++k) s += blkSum[k];
        base_s = s;
    }
    __syncthreads();
    // Hillis-Steele inclusive scan over 256 entries (8 rounds)
    for (int o = 1; o < SCAN_BLK; o <<= 1) {
        int add = (t >= o) ? sm[t - o] : 0;
        __syncthreads();
        sm[t] += add;
        __syncthreads();
    }
    if (i < N_NODES) {
        int excl = base_s + ((t > 0) ? sm[t - 1] : 0);
        offs[i] = excl;
        cursor[i] = excl;
        dinv[i] = rsqrtf((float)(v + 1));  // self-loop included, deg>=1 always
        if (i == N_NODES - 1) offs[N_NODES] = excl + v;
    }
}

// ---------------------------------------------------------------------------
// K3: CSR fill, src index ONLY (norm reconstructed in agg via dinv[src]).
// ---------------------------------------------------------------------------
__global__ __launch_bounds__(256) void fill_k(const int* __restrict__ row,
                                              const int* __restrict__ col,
                                              int* __restrict__ cursor,
                                              int* __restrict__ csr_src) {
    int e = blockIdx.x * blockDim.x + threadIdx.x;
    if (e < N_EDGES) {
        int c = col[e];
        int r = row[e];
        if ((unsigned)c < N_NODES && (unsigned)r < N_NODES) {
            int p = atomicAdd(&cursor[c], 1);
            csr_src[p] = r;
        }
    }
}

// ---------------------------------------------------------------------------
// Shared GEMM helpers: 32-row tile, 4r x 4c per thread. xT transposed in LDS.
// Per-k: ONE b128 broadcast (x rows) + ONE b128 W read per lane.
// ---------------------------------------------------------------------------
__device__ __forceinline__ void stage_xt(float* xt, const float* __restrict__ Xm,
                                         int row0, int t) {
    const int r = t & 31;
    const int kbase = (t >> 5) * 16;
    const float* xp = Xm + (size_t)(row0 + r) * 128 + kbase;
#pragma unroll
    for (int c = 0; c < 4; ++c) {
        float4 v = *(const float4*)&xp[c * 4];
        xt[(kbase + c * 4 + 0) * XT_STRIDE + r] = v.x;
        xt[(kbase + c * 4 + 1) * XT_STRIDE + r] = v.y;
        xt[(kbase + c * 4 + 2) * XT_STRIDE + r] = v.z;
        xt[(kbase + c * 4 + 3) * XT_STRIDE + r] = v.w;
    }
}

__device__ __forceinline__ void gemm_half(const float* xt, const float* wbuf,
                                          int kb, int rg, int c4, float4 acc[4]) {
#pragma unroll 8
    for (int k0 = 0; k0 < 64; ++k0) {
        float4 w = *(const float4*)&wbuf[k0 * 128 + c4];
        float4 xr = *(const float4*)&xt[(kb + k0) * XT_STRIDE + rg * 4];
        acc[0].x = fmaf(xr.x, w.x, acc[0].x);
        acc[0].y = fmaf(xr.x, w.y, acc[0].y);
        acc[0].z = fmaf(xr.x, w.z, acc[0].z);
        acc[0].w = fmaf(xr.x, w.w, acc[0].w);
        acc[1].x = fmaf(xr.y, w.x, acc[1].x);
        acc[1].y = fmaf(xr.y, w.y, acc[1].y);
        acc[1].z = fmaf(xr.y, w.z, acc[1].z);
        acc[1].w = fmaf(xr.y, w.w, acc[1].w);
        acc[2].x = fmaf(xr.z, w.x, acc[2].x);
        acc[2].y = fmaf(xr.z, w.y, acc[2].y);
        acc[2].z = fmaf(xr.z, w.z, acc[2].z);
        acc[2].w = fmaf(xr.z, w.w, acc[2].w);
        acc[3].x = fmaf(xr.w, w.x, acc[3].x);
        acc[3].y = fmaf(xr.w, w.y, acc[3].y);
        acc[3].z = fmaf(xr.w, w.z, acc[3].z);
        acc[3].w = fmaf(xr.w, w.w, acc[3].w);
    }
}

// ---------------------------------------------------------------------------
// K4: Y[20000,128] = X @ W (f32). 625 blocks, 32-row tiles, xT staging.
// ---------------------------------------------------------------------------
__global__ __launch_bounds__(256) void gemm128_k(const float* __restrict__ X,
                                                 const float* __restrict__ W,
                                                 float* __restrict__ Y) {
    __shared__ float wbuf[64 * 128];           // 32 KB
    __shared__ float xt[128 * XT_STRIDE];      // 18 KB (transposed x tile)
    const int t = threadIdx.x;
    const int rg = t >> 5;
    const int c4 = (t & 31) * 4;
    const int row0 = blockIdx.x * 32;
    float4 acc[4];
    acc[0] = acc[1] = acc[2] = acc[3] = make_float4(0.f, 0.f, 0.f, 0.f);
    stage_xt(xt, X, row0, t);
#pragma unroll
    for (int kc = 0; kc < 2; ++kc) {
        if (kc) __syncthreads();
#pragma unroll
        for (int i = 0; i < 8; ++i)
            ((float4*)wbuf)[t + i * 256] = ((const float4*)W)[kc * 2048 + t + i * 256];
        __syncthreads();
        gemm_half(xt, wbuf, kc * 64, rg, c4, acc);
    }
#pragma unroll
    for (int i = 0; i < 4; ++i)
        *(float4*)&Y[(size_t)(row0 + rg * 4 + i) * 128 + c4] = acc[i];
}

// ---------------------------------------------------------------------------
// K5: GCN aggregation. TWO nodes per wave, float4/lane.
// Edge weight = dinv[src]. OOB edge -> index 0, weight 0 (branchless).
// ---------------------------------------------------------------------------
__global__ __launch_bounds__(256) void gcn_agg_k(const float* __restrict__ h,
                                                 const int* __restrict__ offs,
                                                 const int* __restrict__ src,
                                                 const float* __restrict__ dinv,
                                                 const float* __restrict__ bias,
                                                 float* __restrict__ out) {
    const int wave = threadIdx.x >> 6;
    const int lane = threadIdx.x & 63;
    const int half = lane >> 5;
    const int node = (blockIdx.x * 4 + wave) * 2 + half;
    const int c4 = (lane & 31) * 4;
    const int nd = (node < N_NODES) ? node : (N_NODES - 1);
    const float dc = dinv[nd];
    float4 hv = *(const float4*)&h[(size_t)nd * 128 + c4];
    float4 acc = make_float4(dc * hv.x, dc * hv.y, dc * hv.z, dc * hv.w);
    const int beg = offs[nd];
    const int deg = offs[nd + 1] - beg;
    const int mdeg = max(deg, __shfl(deg, lane ^ 32));
    for (int j = 0; j < mdeg; j += 4) {
        int i0 = (j + 0 < deg) ? beg + j + 0 : 0;
        int i1 = (j + 1 < deg) ? beg + j + 1 : 0;
        int i2 = (j + 2 < deg) ? beg + j + 2 : 0;
        int i3 = (j + 3 < deg) ? beg + j + 3 : 0;
        int s0 = src[i0], s1 = src[i1], s2 = src[i2], s3 = src[i3];
        float w0 = (j + 0 < deg) ? dinv[s0] : 0.f;
        float w1 = (j + 1 < deg) ? dinv[s1] : 0.f;
        float w2 = (j + 2 < deg) ? dinv[s2] : 0.f;
        float w3 = (j + 3 < deg) ? dinv[s3] : 0.f;
        float4 v0 = *(const float4*)&h[(size_t)s0 * 128 + c4];
        float4 v1 = *(const float4*)&h[(size_t)s1 * 128 + c4];
        float4 v2 = *(const float4*)&h[(size_t)s2 * 128 + c4];
        float4 v3 = *(const float4*)&h[(size_t)s3 * 128 + c4];
        acc.x = fmaf(w0, v0.x, fmaf(w1, v1.x, fmaf(w2, v2.x, fmaf(w3, v3.x, acc.x))));
        acc.y = fmaf(w0, v0.y, fmaf(w1, v1.y, fmaf(w2, v2.y, fmaf(w3, v3.y, acc.y))));
        acc.z = fmaf(w0, v0.z, fmaf(w1, v1.z, fmaf(w2, v2.z, fmaf(w3, v3.z, acc.z))));
        acc.w = fmaf(w0, v0.w, fmaf(w1, v1.w, fmaf(w2, v2.w, fmaf(w3, v3.w, acc.w))));
    }
    float4 b = *(const float4*)&bias[c4];
    float4 o;
    o.x = fmaxf(fmaf(dc, acc.x, b.x), 0.f);
    o.y = fmaxf(fmaf(dc, acc.y, b.y), 0.f);
    o.z = fmaxf(fmaf(dc, acc.z, b.z), 0.f);
    o.w = fmaxf(fmaf(dc, acc.w, b.w), 0.f);
    if (node < N_NODES) *(float4*)&out[(size_t)node * 128 + c4] = o;
}

// ---------------------------------------------------------------------------
// K6: FUSED sage mean-agg + combine GEMM. 625 blocks x 32 rows.
// Phase A: each wave mean-aggregates 8 nodes (4 pairs, 2/wave) writing neigh
// DIRECTLY into xt transposed (skips the 20 MB global round-trip of neigh).
// Phase B: acc = xt @ Wl. Phase C: restage xt from hg own rows; acc += xt @ Wr.
// Writes bufA rows (own tile only); reads ONLY bufB -> no in-place hazard.
// ---------------------------------------------------------------------------
__global__ __launch_bounds__(256) void fused_sc_k(const float* __restrict__ hg,
                                                  const int* __restrict__ offs,
                                                  const int* __restrict__ src,
                                                  const float* __restrict__ Wl,
                                                  const float* __restrict__ Wr,
                                                  const float* __restrict__ bias,
                                                  float* __restrict__ Y) {
    __shared__ float wbuf[64 * 128];           // 32 KB
    __shared__ float xt[128 * XT_STRIDE];      // 18 KB
    const int t = threadIdx.x;
    const int wave = t >> 6;
    const int lane = t & 63;
    const int half = lane >> 5;
    const int c4 = (lane & 31) * 4;
    const int row0 = blockIdx.x * 32;
    // ---- Phase A: mean-aggregate 32 nodes into xt (transposed) ----
#pragma unroll
    for (int p = 0; p < 4; ++p) {
        const int nodeLocal = wave * 8 + p * 2 + half;
        const int node = row0 + nodeLocal;  // always < N_NODES (20000 = 625*32)
        float4 acc = make_float4(0.f, 0.f, 0.f, 0.f);
        const int beg = offs[node];
        const int deg = offs[node + 1] - beg;
        const int mdeg = max(deg, __shfl(deg, lane ^ 32));
        for (int j = 0; j < mdeg; j += 4) {
            int i0 = (j + 0 < deg) ? beg + j + 0 : 0;
            int i1 = (j + 1 < deg) ? beg + j + 1 : 0;
            int i2 = (j + 2 < deg) ? beg + j + 2 : 0;
            int i3 = (j + 3 < deg) ? beg + j + 3 : 0;
            float w0 = (j + 0 < deg) ? 1.f : 0.f;
            float w1 = (j + 1 < deg) ? 1.f : 0.f;
            float w2 = (j + 2 < deg) ? 1.f : 0.f;
            float w3 = (j + 3 < deg) ? 1.f : 0.f;
            int s0 = src[i0], s1 = src[i1], s2 = src[i2], s3 = src[i3];
            float4 v0 = *(const float4*)&hg[(size_t)s0 * 128 + c4];
            float4 v1 = *(const float4*)&hg[(size_t)s1 * 128 + c4];
            float4 v2 = *(const float4*)&hg[(size_t)s2 * 128 + c4];
            float4 v3 = *(const float4*)&hg[(size_t)s3 * 128 + c4];
            acc.x = fmaf(w0, v0.x, fmaf(w1, v1.x, fmaf(w2, v2.x, fmaf(w3, v3.x, acc.x))));
            acc.y = fmaf(w0, v0.y, fmaf(w1, v1.y, fmaf(w2, v2.y, fmaf(w3, v3.y, acc.y))));
            acc.z = fmaf(w0, v0.z, fmaf(w1, v1.z, fmaf(w2, v2.z, fmaf(w3, v3.z, acc.z))));
            acc.w = fmaf(w0, v0.w, fmaf(w1, v1.w, fmaf(w2, v2.w, fmaf(w3, v3.w, acc.w))));
        }
        const float inv = 1.0f / (float)max(deg, 1);
        xt[(c4 + 0) * XT_STRIDE + nodeLocal] = acc.x * inv;
        xt[(c4 + 1) * XT_STRIDE + nodeLocal] = acc.y * inv;
        xt[(c4 + 2) * XT_STRIDE + nodeLocal] = acc.z * inv;
        xt[(c4 + 3) * XT_STRIDE + nodeLocal] = acc.w * inv;
    }
    // ---- Phases B/C: acc = neigh@Wl + hg_own@Wr + bias, relu ----
    const int rg = t >> 5;
    const int gc4 = (t & 31) * 4;
    float4 acc[4];
    {
        float4 b = *(const float4*)&bias[gc4];
        acc[0] = acc[1] = acc[2] = acc[3] = b;
    }
#pragma unroll
    for (int m = 0; m < 2; ++m) {
        const float* Wm = m ? Wr : Wl;
        if (m) {
            __syncthreads();           // protect xt from phase-B reads
            stage_xt(xt, hg, row0, t); // own h_gcn rows
        }
#pragma unroll
        for (int kc = 0; kc < 2; ++kc) {
            __syncthreads();           // publish xt; protect wbuf from prior reads
#pragma unroll
            for (int i = 0; i < 8; ++i)
                ((float4*)wbuf)[t + i * 256] = ((const float4*)Wm)[kc * 2048 + t + i * 256];
            __syncthreads();
            gemm_half(xt, wbuf, kc * 64, rg, gc4, acc);
        }
    }
#pragma unroll
    for (int i = 0; i < 4; ++i) {
        float4 o = acc[i];
        o.x = fmaxf(o.x, 0.f);
        o.y = fmaxf(o.y, 0.f);
        o.z = fmaxf(o.z, 0.f);
        o.w = fmaxf(o.w, 0.f);
        *(float4*)&Y[(size_t)(row0 + rg * 4 + i) * 128 + gc4] = o;
    }
}

// ---------------------------------------------------------------------------
// K8a: global_add_pool, parallel. Per-thread segmented sum over sorted batch.
// ---------------------------------------------------------------------------
#define POOL_ROWS 64
__global__ __launch_bounds__(256) void pool_k(const float* __restrict__ H,
                                              const int* __restrict__ batch,
                                              float* __restrict__ pooled) {
    const int r0 = blockIdx.x * POOL_ROWS;
    const int t = threadIdx.x;
    const int d = t & 127, half = t >> 7;
    const int rend = min(r0 + POOL_ROWS, N_NODES);
    int i = r0 + half;
    if (i >= rend) return;
    int cur = batch[i];
    float acc = 0.f;
    for (; i < rend; i += 2) {
        int g = batch[i];
        if (g != cur) {
            atomicAdd(&pooled[cur * 128 + d], acc);
            acc = 0.f;
            cur = g;
        }
        acc += H[(size_t)i * 128 + d];
    }
    atomicAdd(&pooled[cur * 128 + d], acc);
}

// ---------------------------------------------------------------------------
// K8b: MLP head. One block per graph, 128 threads.
// ---------------------------------------------------------------------------
__global__ __launch_bounds__(128) void head_k(const float* __restrict__ pooled,
                                              const float* __restrict__ Wfc1,
                                              const float* __restrict__ bfc1,
                                              const float* __restrict__ Wfc2,
                                              const float* __restrict__ bfc2,
                                              float* __restrict__ out) {
    __shared__ float pl[128];
    __shared__ float tmp[128];
    const int g = blockIdx.x;
    const int t = threadIdx.x;
    pl[t] = pooled[g * 128 + t];
    __syncthreads();
    float a = bfc1[t];
#pragma unroll 8
    for (int k = 0; k < 128; ++k) a = fmaf(pl[k], Wfc1[k * 128 + t], a);
    tmp[t] = fmaxf(a, 0.f);
    __syncthreads();
    if (t < 3) {
        float a2 = bfc2[t];
        for (int k = 0; k < 128; ++k) a2 = fmaf(tmp[k], Wfc2[k * 3 + t], a2);
        out[g * 3 + t] = a2;
    }
}

// ---------------------------------------------------------------------------
extern "C" void kernel_launch(void* const* d_in, const int* in_sizes, int n_in,
                              void* d_out, int out_size, void* d_ws, size_t ws_size,
                              hipStream_t stream) {
    const float* x      = (const float*)d_in[0];
    const int*   ei     = (const int*)d_in[1];   // [2, E]: row = ei, col = ei+E
    const int*   batch  = (const int*)d_in[2];
    const float* W_gcn  = (const float*)d_in[3];
    const float* b_gcn  = (const float*)d_in[4];
    const float* W_sl   = (const float*)d_in[5];
    const float* W_sr   = (const float*)d_in[6];
    const float* b_sage = (const float*)d_in[7];
    const float* W_fc1  = (const float*)d_in[8];
    const float* b_fc1  = (const float*)d_in[9];
    const float* W_fc2  = (const float*)d_in[10];
    const float* b_fc2  = (const float*)d_in[11];
    float* out = (float*)d_out;

    char* base = (char*)d_ws;
    size_t off = 0;
    auto take = [&](size_t bytes) -> void* {
        void* p = base + off;
        off += (bytes + 255) & ~(size_t)255;
        return p;
    };
    int*   cnt      = (int*)take((size_t)N_NODES * 4);
    int*   offs     = (int*)take((size_t)(N_NODES + 1) * 4);
    int*   cursor   = (int*)take((size_t)N_NODES * 4);
    float* dinv     = (float*)take((size_t)N_NODES * 4);
    int*   blkSum   = (int*)take((size_t)SCAN_NBLK * 4);
    int*   csr_src  = (int*)take((size_t)N_EDGES * 4);
    float* bufA     = (float*)take((size_t)N_NODES * HID * 4);  // h -> h_sage
    float* bufB     = (float*)take((size_t)N_NODES * HID * 4);  // h_gcn
    float* pooled   = (float*)take((size_t)N_GRAPHS * HID * 4);

    const int* row = ei;
    const int* col = ei + N_EDGES;

    hipMemsetAsync(cnt, 0, (size_t)N_NODES * 4, stream);

    hist_k<<<(N_EDGES + 255) / 256, 256, 0, stream>>>(col, cnt);
    scanA_k<<<SCAN_NBLK, SCAN_BLK, 0, stream>>>(cnt, blkSum);
    scanB_k<<<SCAN_NBLK, SCAN_BLK, 0, stream>>>(cnt, blkSum, offs, cursor, dinv, pooled);
    fill_k<<<(N_EDGES + 255) / 256, 256, 0, stream>>>(row, col, cursor, csr_src);

    const int gemm_blocks = N_NODES / 32;     // 625 (exact)
    const int agg_blocks = (N_NODES + 7) / 8; // 2500 (8 nodes per block)
    // h = x @ W_gcn
    gemm128_k<<<gemm_blocks, 256, 0, stream>>>(x, W_gcn, bufA);
    // h_gcn = relu(aggregate(h) + b_gcn)
    gcn_agg_k<<<agg_blocks, 256, 0, stream>>>(bufA, offs, csr_src, dinv, b_gcn, bufB);
    // h_sage = relu(mean_agg(h_gcn) @ Wl + h_gcn @ Wr + b)  (fused; bufB -> bufA)
    fused_sc_k<<<gemm_blocks, 256, 0, stream>>>(bufB, offs, csr_src, W_sl, W_sr,
                                                b_sage, bufA);
    // pooled (atomic segmented sum) + MLP head
    pool_k<<<(N_NODES + POOL_ROWS - 1) / POOL_ROWS, 256, 0, stream>>>(bufA, batch, pooled);
    head_k<<<N_GRAPHS, 128, 0, stream>>>(pooled, W_fc1, b_fc1, W_fc2, b_fc2, out);
}

// Round 15
// 292.229 us; speedup vs baseline: 1.1293x; 1.0076x over previous
//
#include <hip/hip_runtime.h>

#define N_NODES 20000
#define N_EDGES 640000
#define HID 128
#define N_GRAPHS 32

#define SCAN_BLK 256
#define SCAN_NBLK ((N_NODES + SCAN_BLK - 1) / SCAN_BLK)  // 79

#define XT_STRIDE 36  // padded: 36*4=144 B row stride (16B-aligned)

// ---------------------------------------------------------------------------
// K1: in-degree histogram over target nodes (col)
// ---------------------------------------------------------------------------
__global__ __launch_bounds__(256) void hist_k(const int* __restrict__ col,
                                              int* __restrict__ cnt) {
    int e = blockIdx.x * blockDim.x + threadIdx.x;
    if (e < N_EDGES) {
        int c = col[e];
        if ((unsigned)c < N_NODES) atomicAdd(&cnt[c], 1);
    }
}

// ---------------------------------------------------------------------------
// K2a: per-block sums of cnt (coalesced)
// ---------------------------------------------------------------------------
__global__ __launch_bounds__(SCAN_BLK) void scanA_k(const int* __restrict__ cnt,
                                                    int* __restrict__ blkSum) {
    __shared__ int wsum[SCAN_BLK / 64];
    const int b = blockIdx.x, t = threadIdx.x;
    const int i = b * SCAN_BLK + t;
    int v = (i < N_NODES) ? cnt[i] : 0;
#pragma unroll
    for (int o = 1; o < 64; o <<= 1) v += __shfl_xor(v, o);
    if ((t & 63) == 0) wsum[t >> 6] = v;
    __syncthreads();
    if (t == 0) {
        int s = 0;
#pragma unroll
        for (int w = 0; w < SCAN_BLK / 64; ++w) s += wsum[w];
        blkSum[b] = s;
    }
}

// ---------------------------------------------------------------------------
// K2b: per-block exclusive scan + block base. Block 0 zeroes pooled.
// ---------------------------------------------------------------------------
__global__ __launch_bounds__(SCAN_BLK) void scanB_k(const int* __restrict__ cnt,
                                                    const int* __restrict__ blkSum,
                                                    int* __restrict__ offs,
                                                    int* __restrict__ cursor,
                                                    float* __restrict__ dinv,
                                                    float* __restrict__ pooled) {
    __shared__ int sm[SCAN_BLK];
    __shared__ int base_s;
    const int b = blockIdx.x, t = threadIdx.x;
    const int i = b * SCAN_BLK + t;
    const int v = (i < N_NODES) ? cnt[i] : 0;
    sm[t] = v;
    if (b == 0) {
#pragma unroll
        for (int j = 0; j < (N_GRAPHS * HID) / SCAN_BLK; ++j)
            pooled[j * SCAN_BLK + t] = 0.f;
    }
    if (t == 0) {
        int s = 0;
        for (int k = 0; k < b; ++k) s += blkSum[k];
        base_s = s;
    }
    __syncthreads();
    for (int o = 1; o < SCAN_BLK; o <<= 1) {
        int add = (t >= o) ? sm[t - o] : 0;
        __syncthreads();
        sm[t] += add;
        __syncthreads();
    }
    if (i < N_NODES) {
        int excl = base_s + ((t > 0) ? sm[t - 1] : 0);
        offs[i] = excl;
        cursor[i] = excl;
        dinv[i] = rsqrtf((float)(v + 1));  // self-loop included
        if (i == N_NODES - 1) offs[N_NODES] = excl + v;
    }
}

// ---------------------------------------------------------------------------
// K3: CSR fill, src index only.
// ---------------------------------------------------------------------------
__global__ __launch_bounds__(256) void fill_k(const int* __restrict__ row,
                                              const int* __restrict__ col,
                                              int* __restrict__ cursor,
                                              int* __restrict__ csr_src) {
    int e = blockIdx.x * blockDim.x + threadIdx.x;
    if (e < N_EDGES) {
        int c = col[e];
        int r = row[e];
        if ((unsigned)c < N_NODES && (unsigned)r < N_NODES) {
            int p = atomicAdd(&cursor[c], 1);
            csr_src[p] = r;
        }
    }
}

// ---------------------------------------------------------------------------
// GEMM helpers (verified R12 structure): 32-row tile, xT transposed in LDS.
// ---------------------------------------------------------------------------
__device__ __forceinline__ void stage_xt(float* xt, const float* __restrict__ Xm,
                                         int row0, int t) {
    const int r = t & 31;
    const int kbase = (t >> 5) * 16;
    const float* xp = Xm + (size_t)(row0 + r) * 128 + kbase;
#pragma unroll
    for (int c = 0; c < 4; ++c) {
        float4 v = *(const float4*)&xp[c * 4];
        xt[(kbase + c * 4 + 0) * XT_STRIDE + r] = v.x;
        xt[(kbase + c * 4 + 1) * XT_STRIDE + r] = v.y;
        xt[(kbase + c * 4 + 2) * XT_STRIDE + r] = v.z;
        xt[(kbase + c * 4 + 3) * XT_STRIDE + r] = v.w;
    }
}

__device__ __forceinline__ void stage_w(float* wbuf, const float* __restrict__ Wm,
                                        int kc, int t) {
#pragma unroll
    for (int i = 0; i < 8; ++i)
        ((float4*)wbuf)[t + i * 256] = ((const float4*)Wm)[kc * 2048 + t + i * 256];
}

__device__ __forceinline__ void gemm_half(const float* xt, const float* wbuf,
                                          int kb, int rg, int c4, float4 acc[4]) {
#pragma unroll 8
    for (int k0 = 0; k0 < 64; ++k0) {
        float4 w = *(const float4*)&wbuf[k0 * 128 + c4];
        float4 xr = *(const float4*)&xt[(kb + k0) * XT_STRIDE + rg * 4];
        acc[0].x = fmaf(xr.x, w.x, acc[0].x);
        acc[0].y = fmaf(xr.x, w.y, acc[0].y);
        acc[0].z = fmaf(xr.x, w.z, acc[0].z);
        acc[0].w = fmaf(xr.x, w.w, acc[0].w);
        acc[1].x = fmaf(xr.y, w.x, acc[1].x);
        acc[1].y = fmaf(xr.y, w.y, acc[1].y);
        acc[1].z = fmaf(xr.y, w.z, acc[1].z);
        acc[1].w = fmaf(xr.y, w.w, acc[1].w);
        acc[2].x = fmaf(xr.z, w.x, acc[2].x);
        acc[2].y = fmaf(xr.z, w.y, acc[2].y);
        acc[2].z = fmaf(xr.z, w.z, acc[2].z);
        acc[2].w = fmaf(xr.z, w.w, acc[2].w);
        acc[3].x = fmaf(xr.w, w.x, acc[3].x);
        acc[3].y = fmaf(xr.w, w.y, acc[3].y);
        acc[3].z = fmaf(xr.w, w.z, acc[3].z);
        acc[3].w = fmaf(xr.w, w.w, acc[3].w);
    }
}

// ---------------------------------------------------------------------------
// K4: Y[20000,128] = X @ W (f32). 625 blocks, 32-row tiles, xT staging.
// ---------------------------------------------------------------------------
__global__ __launch_bounds__(256) void gemm128_k(const float* __restrict__ X,
                                                 const float* __restrict__ W,
                                                 float* __restrict__ Y) {
    __shared__ float wbuf[64 * 128];           // 32 KB
    __shared__ float xt[128 * XT_STRIDE];      // 18 KB
    const int t = threadIdx.x;
    const int rg = t >> 5;
    const int c4 = (t & 31) * 4;
    const int row0 = blockIdx.x * 32;
    float4 acc[4];
    acc[0] = acc[1] = acc[2] = acc[3] = make_float4(0.f, 0.f, 0.f, 0.f);
    stage_xt(xt, X, row0, t);
    stage_w(wbuf, W, 0, t);
    __syncthreads();
    gemm_half(xt, wbuf, 0, rg, c4, acc);
    __syncthreads();
    stage_w(wbuf, W, 1, t);
    __syncthreads();
    gemm_half(xt, wbuf, 64, rg, c4, acc);
#pragma unroll
    for (int i = 0; i < 4; ++i)
        *(float4*)&Y[(size_t)(row0 + rg * 4 + i) * 128 + c4] = acc[i];
}

// ---------------------------------------------------------------------------
// K5: GCN aggregation, CHANNEL-SPLIT: pass 0 reads ch 0-63 (row bytes 0-255),
// pass 1 reads ch 64-127. Per-pass gather working set = 5 MB (~L2-resident).
// 4 nodes/wave x 16 lanes x float4. 1250 blocks x 16 nodes (exact).
// ---------------------------------------------------------------------------
__global__ __launch_bounds__(256) void gcn_agg_k(const float* __restrict__ h,
                                                 const int* __restrict__ offs,
                                                 const int* __restrict__ src,
                                                 const float* __restrict__ dinv,
                                                 const float* __restrict__ bias,
                                                 float* __restrict__ out) {
    const int wave = threadIdx.x >> 6;
    const int lane = threadIdx.x & 63;
    const int sub = lane >> 4;                  // node slot 0..3
    const int node = (blockIdx.x * 4 + wave) * 4 + sub;  // 1250*16 = 20000 exact
    const int c0 = (lane & 15) * 4;
    const float dc = dinv[node];
    const int beg = offs[node];
    const int deg = offs[node + 1] - beg;
    int md = max(deg, __shfl(deg, lane ^ 16));
    md = max(md, __shfl(md, lane ^ 32));
#pragma unroll
    for (int pass = 0; pass < 2; ++pass) {
        const int c4 = c0 + pass * 64;
        float4 hv = *(const float4*)&h[(size_t)node * 128 + c4];
        float4 acc = make_float4(dc * hv.x, dc * hv.y, dc * hv.z, dc * hv.w);
        for (int j = 0; j < md; j += 4) {
            int i0 = (j + 0 < deg) ? beg + j + 0 : 0;
            int i1 = (j + 1 < deg) ? beg + j + 1 : 0;
            int i2 = (j + 2 < deg) ? beg + j + 2 : 0;
            int i3 = (j + 3 < deg) ? beg + j + 3 : 0;
            int s0 = src[i0], s1 = src[i1], s2 = src[i2], s3 = src[i3];
            float w0 = (j + 0 < deg) ? dinv[s0] : 0.f;
            float w1 = (j + 1 < deg) ? dinv[s1] : 0.f;
            float w2 = (j + 2 < deg) ? dinv[s2] : 0.f;
            float w3 = (j + 3 < deg) ? dinv[s3] : 0.f;
            float4 v0 = *(const float4*)&h[(size_t)s0 * 128 + c4];
            float4 v1 = *(const float4*)&h[(size_t)s1 * 128 + c4];
            float4 v2 = *(const float4*)&h[(size_t)s2 * 128 + c4];
            float4 v3 = *(const float4*)&h[(size_t)s3 * 128 + c4];
            acc.x = fmaf(w0, v0.x, fmaf(w1, v1.x, fmaf(w2, v2.x, fmaf(w3, v3.x, acc.x))));
            acc.y = fmaf(w0, v0.y, fmaf(w1, v1.y, fmaf(w2, v2.y, fmaf(w3, v3.y, acc.y))));
            acc.z = fmaf(w0, v0.z, fmaf(w1, v1.z, fmaf(w2, v2.z, fmaf(w3, v3.z, acc.z))));
            acc.w = fmaf(w0, v0.w, fmaf(w1, v1.w, fmaf(w2, v2.w, fmaf(w3, v3.w, acc.w))));
        }
        float4 b = *(const float4*)&bias[c4];
        float4 o;
        o.x = fmaxf(fmaf(dc, acc.x, b.x), 0.f);
        o.y = fmaxf(fmaf(dc, acc.y, b.y), 0.f);
        o.z = fmaxf(fmaf(dc, acc.z, b.z), 0.f);
        o.w = fmaxf(fmaf(dc, acc.w, b.w), 0.f);
        *(float4*)&out[(size_t)node * 128 + c4] = o;
    }
}

// ---------------------------------------------------------------------------
// K6: FUSED sage mean-agg + combine GEMM, channel-split phase A.
// Phase A (pass-outer): 4 nodes/wave x 16 lanes, 2 p-iters cover 32 nodes,
// results written transposed into xt. Then staged GEMM phases (Wl, then own
// rows @ Wr). First W-stage hoisted above phase A to overlap.
// Reads only hg (bufB) -> no in-place hazard on Y (bufA).
// ---------------------------------------------------------------------------
__global__ __launch_bounds__(256) void fused_sc_k(const float* __restrict__ hg,
                                                  const int* __restrict__ offs,
                                                  const int* __restrict__ src,
                                                  const float* __restrict__ Wl,
                                                  const float* __restrict__ Wr,
                                                  const float* __restrict__ bias,
                                                  float* __restrict__ Y) {
    __shared__ float wbuf[64 * 128];           // 32 KB
    __shared__ float xt[128 * XT_STRIDE];      // 18 KB
    const int t = threadIdx.x;
    const int wave = t >> 6;
    const int lane = t & 63;
    const int sub = lane >> 4;
    const int c0 = (lane & 15) * 4;
    const int row0 = blockIdx.x * 32;
    stage_w(wbuf, Wl, 0, t);  // overlap Wl-half0 staging with phase A
    // ---- Phase A: mean-agg 32 nodes into xt (transposed), channel-split ----
#pragma unroll
    for (int pass = 0; pass < 2; ++pass) {
        const int c4 = c0 + pass * 64;
#pragma unroll
        for (int p = 0; p < 2; ++p) {
            const int nodeLocal = p * 16 + wave * 4 + sub;  // 0..31
            const int node = row0 + nodeLocal;
            float4 acc = make_float4(0.f, 0.f, 0.f, 0.f);
            const int beg = offs[node];
            const int deg = offs[node + 1] - beg;
            int md = max(deg, __shfl(deg, lane ^ 16));
            md = max(md, __shfl(md, lane ^ 32));
            for (int j = 0; j < md; j += 4) {
                int i0 = (j + 0 < deg) ? beg + j + 0 : 0;
                int i1 = (j + 1 < deg) ? beg + j + 1 : 0;
                int i2 = (j + 2 < deg) ? beg + j + 2 : 0;
                int i3 = (j + 3 < deg) ? beg + j + 3 : 0;
                float w0 = (j + 0 < deg) ? 1.f : 0.f;
                float w1 = (j + 1 < deg) ? 1.f : 0.f;
                float w2 = (j + 2 < deg) ? 1.f : 0.f;
                float w3 = (j + 3 < deg) ? 1.f : 0.f;
                int s0 = src[i0], s1 = src[i1], s2 = src[i2], s3 = src[i3];
                float4 v0 = *(const float4*)&hg[(size_t)s0 * 128 + c4];
                float4 v1 = *(const float4*)&hg[(size_t)s1 * 128 + c4];
                float4 v2 = *(const float4*)&hg[(size_t)s2 * 128 + c4];
                float4 v3 = *(const float4*)&hg[(size_t)s3 * 128 + c4];
                acc.x = fmaf(w0, v0.x, fmaf(w1, v1.x, fmaf(w2, v2.x, fmaf(w3, v3.x, acc.x))));
                acc.y = fmaf(w0, v0.y, fmaf(w1, v1.y, fmaf(w2, v2.y, fmaf(w3, v3.y, acc.y))));
                acc.z = fmaf(w0, v0.z, fmaf(w1, v1.z, fmaf(w2, v2.z, fmaf(w3, v3.z, acc.z))));
                acc.w = fmaf(w0, v0.w, fmaf(w1, v1.w, fmaf(w2, v2.w, fmaf(w3, v3.w, acc.w))));
            }
            const float inv = 1.0f / (float)max(deg, 1);
            xt[(c4 + 0) * XT_STRIDE + nodeLocal] = acc.x * inv;
            xt[(c4 + 1) * XT_STRIDE + nodeLocal] = acc.y * inv;
            xt[(c4 + 2) * XT_STRIDE + nodeLocal] = acc.z * inv;
            xt[(c4 + 3) * XT_STRIDE + nodeLocal] = acc.w * inv;
        }
    }
    __syncthreads();  // xt (neigh) + wbuf (Wl half0) ready
    // ---- GEMM phases ----
    const int rg = t >> 5;
    const int gc4 = (t & 31) * 4;
    float4 acc[4];
    {
        float4 b = *(const float4*)&bias[gc4];
        acc[0] = acc[1] = acc[2] = acc[3] = b;
    }
    gemm_half(xt, wbuf, 0, rg, gc4, acc);         // neigh @ Wl, k 0..63
    __syncthreads();
    stage_w(wbuf, Wl, 1, t);
    __syncthreads();
    gemm_half(xt, wbuf, 64, rg, gc4, acc);        // neigh @ Wl, k 64..127
    __syncthreads();                              // done with xt + wbuf
    stage_xt(xt, hg, row0, t);                    // own h_gcn rows
    stage_w(wbuf, Wr, 0, t);
    __syncthreads();
    gemm_half(xt, wbuf, 0, rg, gc4, acc);         // own @ Wr, k 0..63
    __syncthreads();
    stage_w(wbuf, Wr, 1, t);
    __syncthreads();
    gemm_half(xt, wbuf, 64, rg, gc4, acc);        // own @ Wr, k 64..127
#pragma unroll
    for (int i = 0; i < 4; ++i) {
        float4 o = acc[i];
        o.x = fmaxf(o.x, 0.f);
        o.y = fmaxf(o.y, 0.f);
        o.z = fmaxf(o.z, 0.f);
        o.w = fmaxf(o.w, 0.f);
        *(float4*)&Y[(size_t)(row0 + rg * 4 + i) * 128 + gc4] = o;
    }
}

// ---------------------------------------------------------------------------
// K8a: global_add_pool, parallel segmented sum over sorted batch.
// ---------------------------------------------------------------------------
#define POOL_ROWS 64
__global__ __launch_bounds__(256) void pool_k(const float* __restrict__ H,
                                              const int* __restrict__ batch,
                                              float* __restrict__ pooled) {
    const int r0 = blockIdx.x * POOL_ROWS;
    const int t = threadIdx.x;
    const int d = t & 127, half = t >> 7;
    const int rend = min(r0 + POOL_ROWS, N_NODES);
    int i = r0 + half;
    if (i >= rend) return;
    int cur = batch[i];
    float acc = 0.f;
    for (; i < rend; i += 2) {
        int g = batch[i];
        if (g != cur) {
            atomicAdd(&pooled[cur * 128 + d], acc);
            acc = 0.f;
            cur = g;
        }
        acc += H[(size_t)i * 128 + d];
    }
    atomicAdd(&pooled[cur * 128 + d], acc);
}

// ---------------------------------------------------------------------------
// K8b: MLP head. One block per graph.
// ---------------------------------------------------------------------------
__global__ __launch_bounds__(128) void head_k(const float* __restrict__ pooled,
                                              const float* __restrict__ Wfc1,
                                              const float* __restrict__ bfc1,
                                              const float* __restrict__ Wfc2,
                                              const float* __restrict__ bfc2,
                                              float* __restrict__ out) {
    __shared__ float pl[128];
    __shared__ float tmp[128];
    const int g = blockIdx.x;
    const int t = threadIdx.x;
    pl[t] = pooled[g * 128 + t];
    __syncthreads();
    float a = bfc1[t];
#pragma unroll 8
    for (int k = 0; k < 128; ++k) a = fmaf(pl[k], Wfc1[k * 128 + t], a);
    tmp[t] = fmaxf(a, 0.f);
    __syncthreads();
    if (t < 3) {
        float a2 = bfc2[t];
        for (int k = 0; k < 128; ++k) a2 = fmaf(tmp[k], Wfc2[k * 3 + t], a2);
        out[g * 3 + t] = a2;
    }
}

// ---------------------------------------------------------------------------
extern "C" void kernel_launch(void* const* d_in, const int* in_sizes, int n_in,
                              void* d_out, int out_size, void* d_ws, size_t ws_size,
                              hipStream_t stream) {
    const float* x      = (const float*)d_in[0];
    const int*   ei     = (const int*)d_in[1];   // [2, E]: row = ei, col = ei+E
    const int*   batch  = (const int*)d_in[2];
    const float* W_gcn  = (const float*)d_in[3];
    const float* b_gcn  = (const float*)d_in[4];
    const float* W_sl   = (const float*)d_in[5];
    const float* W_sr   = (const float*)d_in[6];
    const float* b_sage = (const float*)d_in[7];
    const float* W_fc1  = (const float*)d_in[8];
    const float* b_fc1  = (const float*)d_in[9];
    const float* W_fc2  = (const float*)d_in[10];
    const float* b_fc2  = (const float*)d_in[11];
    float* out = (float*)d_out;

    char* base = (char*)d_ws;
    size_t off = 0;
    auto take = [&](size_t bytes) -> void* {
        void* p = base + off;
        off += (bytes + 255) & ~(size_t)255;
        return p;
    };
    int*   cnt      = (int*)take((size_t)N_NODES * 4);
    int*   offs     = (int*)take((size_t)(N_NODES + 1) * 4);
    int*   cursor   = (int*)take((size_t)N_NODES * 4);
    float* dinv     = (float*)take((size_t)N_NODES * 4);
    int*   blkSum   = (int*)take((size_t)SCAN_NBLK * 4);
    int*   csr_src  = (int*)take((size_t)N_EDGES * 4);
    float* bufA     = (float*)take((size_t)N_NODES * HID * 4);  // h -> h_sage
    float* bufB     = (float*)take((size_t)N_NODES * HID * 4);  // h_gcn
    float* pooled   = (float*)take((size_t)N_GRAPHS * HID * 4);

    const int* row = ei;
    const int* col = ei + N_EDGES;

    hipMemsetAsync(cnt, 0, (size_t)N_NODES * 4, stream);

    hist_k<<<(N_EDGES + 255) / 256, 256, 0, stream>>>(col, cnt);
    scanA_k<<<SCAN_NBLK, SCAN_BLK, 0, stream>>>(cnt, blkSum);
    scanB_k<<<SCAN_NBLK, SCAN_BLK, 0, stream>>>(cnt, blkSum, offs, cursor, dinv, pooled);
    fill_k<<<(N_EDGES + 255) / 256, 256, 0, stream>>>(row, col, cursor, csr_src);

    const int gemm_blocks = N_NODES / 32;      // 625 (exact)
    const int agg_blocks  = N_NODES / 16;      // 1250 (exact, 16 nodes/block)
    // h = x @ W_gcn
    gemm128_k<<<gemm_blocks, 256, 0, stream>>>(x, W_gcn, bufA);
    // h_gcn = relu(aggregate(h) + b_gcn)   (channel-split gather)
    gcn_agg_k<<<agg_blocks, 256, 0, stream>>>(bufA, offs, csr_src, dinv, b_gcn, bufB);
    // h_sage = relu(mean_agg(h_gcn) @ Wl + h_gcn @ Wr + b)  (fused; bufB -> bufA)
    fused_sc_k<<<gemm_blocks, 256, 0, stream>>>(bufB, offs, csr_src, W_sl, W_sr,
                                                b_sage, bufA);
    // pooled (atomic segmented sum) + MLP head
    pool_k<<<(N_NODES + POOL_ROWS - 1) / POOL_ROWS, 256, 0, stream>>>(bufA, batch, pooled);
    head_k<<<N_GRAPHS, 128, 0, stream>>>(pooled, W_fc1, b_fc1, W_fc2, b_fc2, out);
}

// Round 16
// 286.140 us; speedup vs baseline: 1.1533x; 1.0213x over previous
//
#include <hip/hip_runtime.h>

#define N_NODES 20000
#define N_EDGES 640000
#define HID 128
#define N_GRAPHS 32

#define SCAN_BLK 256
#define SCAN_NBLK ((N_NODES + SCAN_BLK - 1) / SCAN_BLK)  // 79

#define XT_STRIDE 36  // padded: 36*4=144 B row stride (16B-aligned)

// ---------------------------------------------------------------------------
// K1: in-degree histogram over target nodes (col)
// ---------------------------------------------------------------------------
__global__ __launch_bounds__(256) void hist_k(const int* __restrict__ col,
                                              int* __restrict__ cnt) {
    int e = blockIdx.x * blockDim.x + threadIdx.x;
    if (e < N_EDGES) {
        int c = col[e];
        if ((unsigned)c < N_NODES) atomicAdd(&cnt[c], 1);
    }
}

// ---------------------------------------------------------------------------
// K2a: per-block sums of cnt (coalesced)
// ---------------------------------------------------------------------------
__global__ __launch_bounds__(SCAN_BLK) void scanA_k(const int* __restrict__ cnt,
                                                    int* __restrict__ blkSum) {
    __shared__ int wsum[SCAN_BLK / 64];
    const int b = blockIdx.x, t = threadIdx.x;
    const int i = b * SCAN_BLK + t;
    int v = (i < N_NODES) ? cnt[i] : 0;
#pragma unroll
    for (int o = 1; o < 64; o <<= 1) v += __shfl_xor(v, o);
    if ((t & 63) == 0) wsum[t >> 6] = v;
    __syncthreads();
    if (t == 0) {
        int s = 0;
#pragma unroll
        for (int w = 0; w < SCAN_BLK / 64; ++w) s += wsum[w];
        blkSum[b] = s;
    }
}

// ---------------------------------------------------------------------------
// K2b: per-block exclusive scan + block base. Block 0 zeroes pooled.
// ---------------------------------------------------------------------------
__global__ __launch_bounds__(SCAN_BLK) void scanB_k(const int* __restrict__ cnt,
                                                    const int* __restrict__ blkSum,
                                                    int* __restrict__ offs,
                                                    int* __restrict__ cursor,
                                                    float* __restrict__ dinv,
                                                    float* __restrict__ pooled) {
    __shared__ int sm[SCAN_BLK];
    __shared__ int base_s;
    const int b = blockIdx.x, t = threadIdx.x;
    const int i = b * SCAN_BLK + t;
    const int v = (i < N_NODES) ? cnt[i] : 0;
    sm[t] = v;
    if (b == 0) {
#pragma unroll
        for (int j = 0; j < (N_GRAPHS * HID) / SCAN_BLK; ++j)
            pooled[j * SCAN_BLK + t] = 0.f;
    }
    if (t == 0) {
        int s = 0;
        for (int k = 0; k < b; ++k) s += blkSum[k];
        base_s = s;
    }
    __syncthreads();
    for (int o = 1; o < SCAN_BLK; o <<= 1) {
        int add = (t >= o) ? sm[t - o] : 0;
        __syncthreads();
        sm[t] += add;
        __syncthreads();
    }
    if (i < N_NODES) {
        int excl = base_s + ((t > 0) ? sm[t - 1] : 0);
        offs[i] = excl;
        cursor[i] = excl;
        dinv[i] = rsqrtf((float)(v + 1));  // self-loop included
        if (i == N_NODES - 1) offs[N_NODES] = excl + v;
    }
}

// ---------------------------------------------------------------------------
// K3: CSR fill, src index only.
// ---------------------------------------------------------------------------
__global__ __launch_bounds__(256) void fill_k(const int* __restrict__ row,
                                              const int* __restrict__ col,
                                              int* __restrict__ cursor,
                                              int* __restrict__ csr_src) {
    int e = blockIdx.x * blockDim.x + threadIdx.x;
    if (e < N_EDGES) {
        int c = col[e];
        int r = row[e];
        if ((unsigned)c < N_NODES && (unsigned)r < N_NODES) {
            int p = atomicAdd(&cursor[c], 1);
            csr_src[p] = r;
        }
    }
}

// ---------------------------------------------------------------------------
// GEMM helpers (verified R12 structure): 32-row tile, xT transposed in LDS.
// ---------------------------------------------------------------------------
__device__ __forceinline__ void stage_xt(float* xt, const float* __restrict__ Xm,
                                         int row0, int t) {
    const int r = t & 31;
    const int kbase = (t >> 5) * 16;
    const float* xp = Xm + (size_t)(row0 + r) * 128 + kbase;
#pragma unroll
    for (int c = 0; c < 4; ++c) {
        float4 v = *(const float4*)&xp[c * 4];
        xt[(kbase + c * 4 + 0) * XT_STRIDE + r] = v.x;
        xt[(kbase + c * 4 + 1) * XT_STRIDE + r] = v.y;
        xt[(kbase + c * 4 + 2) * XT_STRIDE + r] = v.z;
        xt[(kbase + c * 4 + 3) * XT_STRIDE + r] = v.w;
    }
}

__device__ __forceinline__ void stage_w(float* wbuf, const float* __restrict__ Wm,
                                        int kc, int t) {
#pragma unroll
    for (int i = 0; i < 8; ++i)
        ((float4*)wbuf)[t + i * 256] = ((const float4*)Wm)[kc * 2048 + t + i * 256];
}

__device__ __forceinline__ void gemm_half(const float* xt, const float* wbuf,
                                          int kb, int rg, int c4, float4 acc[4]) {
#pragma unroll 8
    for (int k0 = 0; k0 < 64; ++k0) {
        float4 w = *(const float4*)&wbuf[k0 * 128 + c4];
        float4 xr = *(const float4*)&xt[(kb + k0) * XT_STRIDE + rg * 4];
        acc[0].x = fmaf(xr.x, w.x, acc[0].x);
        acc[0].y = fmaf(xr.x, w.y, acc[0].y);
        acc[0].z = fmaf(xr.x, w.z, acc[0].z);
        acc[0].w = fmaf(xr.x, w.w, acc[0].w);
        acc[1].x = fmaf(xr.y, w.x, acc[1].x);
        acc[1].y = fmaf(xr.y, w.y, acc[1].y);
        acc[1].z = fmaf(xr.y, w.z, acc[1].z);
        acc[1].w = fmaf(xr.y, w.w, acc[1].w);
        acc[2].x = fmaf(xr.z, w.x, acc[2].x);
        acc[2].y = fmaf(xr.z, w.y, acc[2].y);
        acc[2].z = fmaf(xr.z, w.z, acc[2].z);
        acc[2].w = fmaf(xr.z, w.w, acc[2].w);
        acc[3].x = fmaf(xr.w, w.x, acc[3].x);
        acc[3].y = fmaf(xr.w, w.y, acc[3].y);
        acc[3].z = fmaf(xr.w, w.z, acc[3].z);
        acc[3].w = fmaf(xr.w, w.w, acc[3].w);
    }
}

// ---------------------------------------------------------------------------
// K4: Y[20000,128] = X @ W (f32). 625 blocks, 32-row tiles, xT staging.
// ---------------------------------------------------------------------------
__global__ __launch_bounds__(256) void gemm128_k(const float* __restrict__ X,
                                                 const float* __restrict__ W,
                                                 float* __restrict__ Y) {
    __shared__ float wbuf[64 * 128];           // 32 KB
    __shared__ float xt[128 * XT_STRIDE];      // 18 KB
    const int t = threadIdx.x;
    const int rg = t >> 5;
    const int c4 = (t & 31) * 4;
    const int row0 = blockIdx.x * 32;
    float4 acc[4];
    acc[0] = acc[1] = acc[2] = acc[3] = make_float4(0.f, 0.f, 0.f, 0.f);
    stage_xt(xt, X, row0, t);
    stage_w(wbuf, W, 0, t);
    __syncthreads();
    gemm_half(xt, wbuf, 0, rg, c4, acc);
    __syncthreads();
    stage_w(wbuf, W, 1, t);
    __syncthreads();
    gemm_half(xt, wbuf, 64, rg, c4, acc);
#pragma unroll
    for (int i = 0; i < 4; ++i)
        *(float4*)&Y[(size_t)(row0 + rg * 4 + i) * 128 + c4] = acc[i];
}

// ---------------------------------------------------------------------------
// K5: GCN aggregation, INTERLEAVED full-row gathers: per j-step load 4 src
// indices once and issue 8 float4 gathers (both 256B halves of each row) ->
// 2x memory-level parallelism vs channel-split, half the index overhead.
// 4 nodes/wave x 16 lanes. 1250 blocks x 16 nodes (exact).
// ---------------------------------------------------------------------------
__global__ __launch_bounds__(256) void gcn_agg_k(const float* __restrict__ h,
                                                 const int* __restrict__ offs,
                                                 const int* __restrict__ src,
                                                 const float* __restrict__ dinv,
                                                 const float* __restrict__ bias,
                                                 float* __restrict__ out) {
    const int wave = threadIdx.x >> 6;
    const int lane = threadIdx.x & 63;
    const int sub = lane >> 4;                  // node slot 0..3
    const int node = (blockIdx.x * 4 + wave) * 4 + sub;  // 1250*16 = 20000 exact
    const int c4 = (lane & 15) * 4;             // channels c4 and c4+64
    const float dc = dinv[node];
    const int beg = offs[node];
    const int deg = offs[node + 1] - beg;
    int md = max(deg, __shfl(deg, lane ^ 16));
    md = max(md, __shfl(md, lane ^ 32));
    float4 hv0 = *(const float4*)&h[(size_t)node * 128 + c4];
    float4 hv1 = *(const float4*)&h[(size_t)node * 128 + c4 + 64];
    float4 acc0 = make_float4(dc * hv0.x, dc * hv0.y, dc * hv0.z, dc * hv0.w);
    float4 acc1 = make_float4(dc * hv1.x, dc * hv1.y, dc * hv1.z, dc * hv1.w);
    for (int j = 0; j < md; j += 4) {
        int i0 = (j + 0 < deg) ? beg + j + 0 : 0;
        int i1 = (j + 1 < deg) ? beg + j + 1 : 0;
        int i2 = (j + 2 < deg) ? beg + j + 2 : 0;
        int i3 = (j + 3 < deg) ? beg + j + 3 : 0;
        int s0 = src[i0], s1 = src[i1], s2 = src[i2], s3 = src[i3];
        float w0 = (j + 0 < deg) ? dinv[s0] : 0.f;
        float w1 = (j + 1 < deg) ? dinv[s1] : 0.f;
        float w2 = (j + 2 < deg) ? dinv[s2] : 0.f;
        float w3 = (j + 3 < deg) ? dinv[s3] : 0.f;
        float4 a0 = *(const float4*)&h[(size_t)s0 * 128 + c4];
        float4 b0 = *(const float4*)&h[(size_t)s0 * 128 + c4 + 64];
        float4 a1 = *(const float4*)&h[(size_t)s1 * 128 + c4];
        float4 b1 = *(const float4*)&h[(size_t)s1 * 128 + c4 + 64];
        float4 a2 = *(const float4*)&h[(size_t)s2 * 128 + c4];
        float4 b2 = *(const float4*)&h[(size_t)s2 * 128 + c4 + 64];
        float4 a3 = *(const float4*)&h[(size_t)s3 * 128 + c4];
        float4 b3 = *(const float4*)&h[(size_t)s3 * 128 + c4 + 64];
        acc0.x = fmaf(w0, a0.x, fmaf(w1, a1.x, fmaf(w2, a2.x, fmaf(w3, a3.x, acc0.x))));
        acc0.y = fmaf(w0, a0.y, fmaf(w1, a1.y, fmaf(w2, a2.y, fmaf(w3, a3.y, acc0.y))));
        acc0.z = fmaf(w0, a0.z, fmaf(w1, a1.z, fmaf(w2, a2.z, fmaf(w3, a3.z, acc0.z))));
        acc0.w = fmaf(w0, a0.w, fmaf(w1, a1.w, fmaf(w2, a2.w, fmaf(w3, a3.w, acc0.w))));
        acc1.x = fmaf(w0, b0.x, fmaf(w1, b1.x, fmaf(w2, b2.x, fmaf(w3, b3.x, acc1.x))));
        acc1.y = fmaf(w0, b0.y, fmaf(w1, b1.y, fmaf(w2, b2.y, fmaf(w3, b3.y, acc1.y))));
        acc1.z = fmaf(w0, b0.z, fmaf(w1, b1.z, fmaf(w2, b2.z, fmaf(w3, b3.z, acc1.z))));
        acc1.w = fmaf(w0, b0.w, fmaf(w1, b1.w, fmaf(w2, b2.w, fmaf(w3, b3.w, acc1.w))));
    }
    float4 bb0 = *(const float4*)&bias[c4];
    float4 bb1 = *(const float4*)&bias[c4 + 64];
    float4 o0, o1;
    o0.x = fmaxf(fmaf(dc, acc0.x, bb0.x), 0.f);
    o0.y = fmaxf(fmaf(dc, acc0.y, bb0.y), 0.f);
    o0.z = fmaxf(fmaf(dc, acc0.z, bb0.z), 0.f);
    o0.w = fmaxf(fmaf(dc, acc0.w, bb0.w), 0.f);
    o1.x = fmaxf(fmaf(dc, acc1.x, bb1.x), 0.f);
    o1.y = fmaxf(fmaf(dc, acc1.y, bb1.y), 0.f);
    o1.z = fmaxf(fmaf(dc, acc1.z, bb1.z), 0.f);
    o1.w = fmaxf(fmaf(dc, acc1.w, bb1.w), 0.f);
    *(float4*)&out[(size_t)node * 128 + c4] = o0;
    *(float4*)&out[(size_t)node * 128 + c4 + 64] = o1;
}

// ---------------------------------------------------------------------------
// K6: FUSED sage mean-agg + combine GEMM, interleaved full-row gathers in
// phase A (8 gathers in flight per j-step). Then staged GEMM phases.
// Reads only hg (bufB) -> no in-place hazard on Y (bufA).
// ---------------------------------------------------------------------------
__global__ __launch_bounds__(256) void fused_sc_k(const float* __restrict__ hg,
                                                  const int* __restrict__ offs,
                                                  const int* __restrict__ src,
                                                  const float* __restrict__ Wl,
                                                  const float* __restrict__ Wr,
                                                  const float* __restrict__ bias,
                                                  float* __restrict__ Y) {
    __shared__ float wbuf[64 * 128];           // 32 KB
    __shared__ float xt[128 * XT_STRIDE];      // 18 KB
    const int t = threadIdx.x;
    const int wave = t >> 6;
    const int lane = t & 63;
    const int sub = lane >> 4;
    const int c4 = (lane & 15) * 4;
    const int row0 = blockIdx.x * 32;
    stage_w(wbuf, Wl, 0, t);  // overlap Wl-half0 staging with phase A
    // ---- Phase A: mean-agg 32 nodes into xt (transposed), full rows ----
#pragma unroll
    for (int p = 0; p < 2; ++p) {
        const int nodeLocal = p * 16 + wave * 4 + sub;  // 0..31
        const int node = row0 + nodeLocal;
        float4 acc0 = make_float4(0.f, 0.f, 0.f, 0.f);
        float4 acc1 = make_float4(0.f, 0.f, 0.f, 0.f);
        const int beg = offs[node];
        const int deg = offs[node + 1] - beg;
        int md = max(deg, __shfl(deg, lane ^ 16));
        md = max(md, __shfl(md, lane ^ 32));
        for (int j = 0; j < md; j += 4) {
            int i0 = (j + 0 < deg) ? beg + j + 0 : 0;
            int i1 = (j + 1 < deg) ? beg + j + 1 : 0;
            int i2 = (j + 2 < deg) ? beg + j + 2 : 0;
            int i3 = (j + 3 < deg) ? beg + j + 3 : 0;
            float w0 = (j + 0 < deg) ? 1.f : 0.f;
            float w1 = (j + 1 < deg) ? 1.f : 0.f;
            float w2 = (j + 2 < deg) ? 1.f : 0.f;
            float w3 = (j + 3 < deg) ? 1.f : 0.f;
            int s0 = src[i0], s1 = src[i1], s2 = src[i2], s3 = src[i3];
            float4 a0 = *(const float4*)&hg[(size_t)s0 * 128 + c4];
            float4 b0 = *(const float4*)&hg[(size_t)s0 * 128 + c4 + 64];
            float4 a1 = *(const float4*)&hg[(size_t)s1 * 128 + c4];
            float4 b1 = *(const float4*)&hg[(size_t)s1 * 128 + c4 + 64];
            float4 a2 = *(const float4*)&hg[(size_t)s2 * 128 + c4];
            float4 b2 = *(const float4*)&hg[(size_t)s2 * 128 + c4 + 64];
            float4 a3 = *(const float4*)&hg[(size_t)s3 * 128 + c4];
            float4 b3 = *(const float4*)&hg[(size_t)s3 * 128 + c4 + 64];
            acc0.x = fmaf(w0, a0.x, fmaf(w1, a1.x, fmaf(w2, a2.x, fmaf(w3, a3.x, acc0.x))));
            acc0.y = fmaf(w0, a0.y, fmaf(w1, a1.y, fmaf(w2, a2.y, fmaf(w3, a3.y, acc0.y))));
            acc0.z = fmaf(w0, a0.z, fmaf(w1, a1.z, fmaf(w2, a2.z, fmaf(w3, a3.z, acc0.z))));
            acc0.w = fmaf(w0, a0.w, fmaf(w1, a1.w, fmaf(w2, a2.w, fmaf(w3, a3.w, acc0.w))));
            acc1.x = fmaf(w0, b0.x, fmaf(w1, b1.x, fmaf(w2, b2.x, fmaf(w3, b3.x, acc1.x))));
            acc1.y = fmaf(w0, b0.y, fmaf(w1, b1.y, fmaf(w2, b2.y, fmaf(w3, b3.y, acc1.y))));
            acc1.z = fmaf(w0, b0.z, fmaf(w1, b1.z, fmaf(w2, b2.z, fmaf(w3, b3.z, acc1.z))));
            acc1.w = fmaf(w0, b0.w, fmaf(w1, b1.w, fmaf(w2, b2.w, fmaf(w3, b3.w, acc1.w))));
        }
        const float inv = 1.0f / (float)max(deg, 1);
        xt[(c4 + 0) * XT_STRIDE + nodeLocal] = acc0.x * inv;
        xt[(c4 + 1) * XT_STRIDE + nodeLocal] = acc0.y * inv;
        xt[(c4 + 2) * XT_STRIDE + nodeLocal] = acc0.z * inv;
        xt[(c4 + 3) * XT_STRIDE + nodeLocal] = acc0.w * inv;
        xt[(c4 + 64) * XT_STRIDE + nodeLocal] = acc1.x * inv;
        xt[(c4 + 65) * XT_STRIDE + nodeLocal] = acc1.y * inv;
        xt[(c4 + 66) * XT_STRIDE + nodeLocal] = acc1.z * inv;
        xt[(c4 + 67) * XT_STRIDE + nodeLocal] = acc1.w * inv;
    }
    __syncthreads();  // xt (neigh) + wbuf (Wl half0) ready
    // ---- GEMM phases ----
    const int rg = t >> 5;
    const int gc4 = (t & 31) * 4;
    float4 acc[4];
    {
        float4 b = *(const float4*)&bias[gc4];
        acc[0] = acc[1] = acc[2] = acc[3] = b;
    }
    gemm_half(xt, wbuf, 0, rg, gc4, acc);         // neigh @ Wl, k 0..63
    __syncthreads();
    stage_w(wbuf, Wl, 1, t);
    __syncthreads();
    gemm_half(xt, wbuf, 64, rg, gc4, acc);        // neigh @ Wl, k 64..127
    __syncthreads();                              // done with xt + wbuf
    stage_xt(xt, hg, row0, t);                    // own h_gcn rows
    stage_w(wbuf, Wr, 0, t);
    __syncthreads();
    gemm_half(xt, wbuf, 0, rg, gc4, acc);         // own @ Wr, k 0..63
    __syncthreads();
    stage_w(wbuf, Wr, 1, t);
    __syncthreads();
    gemm_half(xt, wbuf, 64, rg, gc4, acc);        // own @ Wr, k 64..127
#pragma unroll
    for (int i = 0; i < 4; ++i) {
        float4 o = acc[i];
        o.x = fmaxf(o.x, 0.f);
        o.y = fmaxf(o.y, 0.f);
        o.z = fmaxf(o.z, 0.f);
        o.w = fmaxf(o.w, 0.f);
        *(float4*)&Y[(size_t)(row0 + rg * 4 + i) * 128 + gc4] = o;
    }
}

// ---------------------------------------------------------------------------
// K8a: global_add_pool, parallel segmented sum over sorted batch.
// ---------------------------------------------------------------------------
#define POOL_ROWS 64
__global__ __launch_bounds__(256) void pool_k(const float* __restrict__ H,
                                              const int* __restrict__ batch,
                                              float* __restrict__ pooled) {
    const int r0 = blockIdx.x * POOL_ROWS;
    const int t = threadIdx.x;
    const int d = t & 127, half = t >> 7;
    const int rend = min(r0 + POOL_ROWS, N_NODES);
    int i = r0 + half;
    if (i >= rend) return;
    int cur = batch[i];
    float acc = 0.f;
    for (; i < rend; i += 2) {
        int g = batch[i];
        if (g != cur) {
            atomicAdd(&pooled[cur * 128 + d], acc);
            acc = 0.f;
            cur = g;
        }
        acc += H[(size_t)i * 128 + d];
    }
    atomicAdd(&pooled[cur * 128 + d], acc);
}

// ---------------------------------------------------------------------------
// K8b: MLP head. One block per graph.
// ---------------------------------------------------------------------------
__global__ __launch_bounds__(128) void head_k(const float* __restrict__ pooled,
                                              const float* __restrict__ Wfc1,
                                              const float* __restrict__ bfc1,
                                              const float* __restrict__ Wfc2,
                                              const float* __restrict__ bfc2,
                                              float* __restrict__ out) {
    __shared__ float pl[128];
    __shared__ float tmp[128];
    const int g = blockIdx.x;
    const int t = threadIdx.x;
    pl[t] = pooled[g * 128 + t];
    __syncthreads();
    float a = bfc1[t];
#pragma unroll 8
    for (int k = 0; k < 128; ++k) a = fmaf(pl[k], Wfc1[k * 128 + t], a);
    tmp[t] = fmaxf(a, 0.f);
    __syncthreads();
    if (t < 3) {
        float a2 = bfc2[t];
        for (int k = 0; k < 128; ++k) a2 = fmaf(tmp[k], Wfc2[k * 3 + t], a2);
        out[g * 3 + t] = a2;
    }
}

// ---------------------------------------------------------------------------
extern "C" void kernel_launch(void* const* d_in, const int* in_sizes, int n_in,
                              void* d_out, int out_size, void* d_ws, size_t ws_size,
                              hipStream_t stream) {
    const float* x      = (const float*)d_in[0];
    const int*   ei     = (const int*)d_in[1];   // [2, E]: row = ei, col = ei+E
    const int*   batch  = (const int*)d_in[2];
    const float* W_gcn  = (const float*)d_in[3];
    const float* b_gcn  = (const float*)d_in[4];
    const float* W_sl   = (const float*)d_in[5];
    const float* W_sr   = (const float*)d_in[6];
    const float* b_sage = (const float*)d_in[7];
    const float* W_fc1  = (const float*)d_in[8];
    const float* b_fc1  = (const float*)d_in[9];
    const float* W_fc2  = (const float*)d_in[10];
    const float* b_fc2  = (const float*)d_in[11];
    float* out = (float*)d_out;

    char* base = (char*)d_ws;
    size_t off = 0;
    auto take = [&](size_t bytes) -> void* {
        void* p = base + off;
        off += (bytes + 255) & ~(size_t)255;
        return p;
    };
    int*   cnt      = (int*)take((size_t)N_NODES * 4);
    int*   offs     = (int*)take((size_t)(N_NODES + 1) * 4);
    int*   cursor   = (int*)take((size_t)N_NODES * 4);
    float* dinv     = (float*)take((size_t)N_NODES * 4);
    int*   blkSum   = (int*)take((size_t)SCAN_NBLK * 4);
    int*   csr_src  = (int*)take((size_t)N_EDGES * 4);
    float* bufA     = (float*)take((size_t)N_NODES * HID * 4);  // h -> h_sage
    float* bufB     = (float*)take((size_t)N_NODES * HID * 4);  // h_gcn
    float* pooled   = (float*)take((size_t)N_GRAPHS * HID * 4);

    const int* row = ei;
    const int* col = ei + N_EDGES;

    hipMemsetAsync(cnt, 0, (size_t)N_NODES * 4, stream);

    hist_k<<<(N_EDGES + 255) / 256, 256, 0, stream>>>(col, cnt);
    scanA_k<<<SCAN_NBLK, SCAN_BLK, 0, stream>>>(cnt, blkSum);
    scanB_k<<<SCAN_NBLK, SCAN_BLK, 0, stream>>>(cnt, blkSum, offs, cursor, dinv, pooled);
    fill_k<<<(N_EDGES + 255) / 256, 256, 0, stream>>>(row, col, cursor, csr_src);

    const int gemm_blocks = N_NODES / 32;      // 625 (exact)
    const int agg_blocks  = N_NODES / 16;      // 1250 (exact, 16 nodes/block)
    // h = x @ W_gcn
    gemm128_k<<<gemm_blocks, 256, 0, stream>>>(x, W_gcn, bufA);
    // h_gcn = relu(aggregate(h) + b_gcn)   (interleaved full-row gathers)
    gcn_agg_k<<<agg_blocks, 256, 0, stream>>>(bufA, offs, csr_src, dinv, b_gcn, bufB);
    // h_sage = relu(mean_agg(h_gcn) @ Wl + h_gcn @ Wr + b)  (fused; bufB -> bufA)
    fused_sc_k<<<gemm_blocks, 256, 0, stream>>>(bufB, offs, csr_src, W_sl, W_sr,
                                                b_sage, bufA);
    // pooled (atomic segmented sum) + MLP head
    pool_k<<<(N_NODES + POOL_ROWS - 1) / POOL_ROWS, 256, 0, stream>>>(bufA, batch, pooled);
    head_k<<<N_GRAPHS, 128, 0, stream>>>(pooled, W_fc1, b_fc1, W_fc2, b_fc2, out);
}